// Round 2
// 587.468 us; speedup vs baseline: 1.0770x; 1.0770x over previous
//
#include <hip/hip_runtime.h>

// Problem constants
#define B_    2
#define T_    2048
#define HID_  2048
#define NH_   32
#define NKV_  8
#define HD_   64
#define STEPS_ 2
#define SCALE_ 0.125f
// SCALE * log2(e): scores kept in exp2 domain throughout (folded into q at RoPE)
#define CSC_  0.18033688011112042f

typedef float   f32x4  __attribute__((ext_vector_type(4)));
typedef __bf16  bf16x8 __attribute__((ext_vector_type(8)));
typedef unsigned short u16x8 __attribute__((ext_vector_type(8)));

__device__ __forceinline__ unsigned short f2bf(float f) {
  unsigned int u = __builtin_bit_cast(unsigned int, f);
  u = (u + 0x7fffu + ((u >> 16) & 1u)) >> 16;
  return (unsigned short)u;
}
__device__ __forceinline__ float bf2f(unsigned short h) {
  unsigned int u = ((unsigned int)h) << 16;
  return __builtin_bit_cast(float, u);
}
__device__ __forceinline__ bf16x8 frag_ld(const unsigned short* p) {
  u16x8 v = *(const u16x8*)p;
  return __builtin_bit_cast(bf16x8, v);
}
__device__ __forceinline__ f32x4 mfma16(bf16x8 a, bf16x8 b, f32x4 c) {
  return __builtin_amdgcn_mfma_f32_16x16x32_bf16(a, b, c, 0, 0, 0);
}
__device__ __forceinline__ void async_cp16(const void* g, void* l) {
  __builtin_amdgcn_global_load_lds(
      (const __attribute__((address_space(1))) void*)g,
      (__attribute__((address_space(3))) void*)l, 16, 0, 0);
}

// ---------------------------------------------------------------------------
// elementwise fp32 -> bf16 convert (float4 per thread)
__global__ __launch_bounds__(256) void convert_bf16(const float* __restrict__ in,
                                                    unsigned short* __restrict__ out,
                                                    int n4) {
  int idx = blockIdx.x * 256 + threadIdx.x;
  if (idx < n4) {
    float4 v = ((const float4*)in)[idx];
    ushort4 o;
    o.x = f2bf(v.x); o.y = f2bf(v.y); o.z = f2bf(v.z); o.w = f2bf(v.w);
    ((ushort4*)out)[idx] = o;
  }
}

// transpose + convert: in (K x N fp32 row-major) -> out (N x K bf16, ld=ldo)
__global__ __launch_bounds__(256) void transpose_f32_bf16_ld(const float* __restrict__ in,
                                                             unsigned short* __restrict__ out,
                                                             int K, int N, int ldo) {
  __shared__ float tile[64][65];
  int n0 = blockIdx.x * 64, k0 = blockIdx.y * 64;
  int c = threadIdx.x & 63, w = threadIdx.x >> 6;
#pragma unroll
  for (int i = 0; i < 16; i++) {
    int r = w * 16 + i;
    tile[r][c] = in[(size_t)(k0 + r) * N + n0 + c];
  }
  __syncthreads();
#pragma unroll
  for (int i = 0; i < 16; i++) {
    int rr = w * 16 + i;
    out[(size_t)(n0 + rr) * ldo + k0 + c] = f2bf(tile[c][rr]);
  }
}

// v0 (B*NH slabs of [T][D] fp32) -> v0t bf16 [B*NH][D][T]
__global__ __launch_bounds__(256) void transpose_v0(const float* __restrict__ v0,
                                                    unsigned short* __restrict__ v0t) {
  __shared__ float tile[64][65];
  int s0 = blockIdx.x * 64;
  int bh = blockIdx.y;
  const float* src = v0 + (size_t)bh * T_ * HD_;
  unsigned short* dst = v0t + (size_t)bh * HD_ * T_;
  int c = threadIdx.x & 63, w = threadIdx.x >> 6;
#pragma unroll
  for (int i = 0; i < 16; i++) {
    int r = w * 16 + i;
    tile[r][c] = src[(size_t)(s0 + r) * HD_ + c];
  }
  __syncthreads();
#pragma unroll
  for (int i = 0; i < 16; i++) {
    int rr = w * 16 + i;
    dst[(size_t)rr * T_ + s0 + c] = f2bf(tile[c][rr]);
  }
}

// ---------------------------------------------------------------------------
// 256x256 8-phase bf16 GEMM: C(MxN fp32) = A(MxK) * Bt(NxK)^T
//
// Template: BM=BN=256, BK=64, 8 waves (2M x 4N), per-wave C = 128x64.
// LDS 128 KiB = 2 dbuf x {A0,A1,B0,B1} halves (128 rows x 64 K, 16 KiB each).
// Swizzle: logical 16B-slot s (addr bits 4-6) stored at s ^ (row&7); realized
// as linear global_load_lds dest + inverse-permuted global source; readers
// apply the same XOR -> conflict-free ds_read_b128 (8 lanes/slot-group = 2
// lanes/bank over the wave, free per m136).
//
// Phase ledger per iteration i (tiles e=2i in buf0, o=2i+1 in buf1):
//  P1: rdA(b0,qm0)+rdB(b0,qn0) [12 ds] | stage b1.A0 <- tile o  | mma(0,0)
//  P2: rdB(b0,qn1)             [ 4 ds] | stage b1.A1 <- tile o  | mma(0,1)
//  P3: rdA(b0,qm1)             [ 8 ds] | stage b0.B0 <- e+2     | mma(1,1)
//  P4:                                 | stage b0.B1 <- e+2     | mma(1,0) vmcnt(4)
//  P5: rdA(b1,qm0)+rdB(b1,qn0)         | stage b0.A0 <- e+2     | mma(0,0)
//  P6: rdB(b1,qn1)                     | stage b0.A1 <- e+2     | mma(0,1)
//  P7: rdA(b1,qm1)                     | stage b1.B0 <- e+3     | mma(1,1)
//  P8:                                 | stage b1.B1 <- e+3     | mma(1,0) vmcnt(4)
// Race-freedom: B halves' last ds-read is P2/P6, A halves' P3/P7; every stage
// of a region is issued >=1 full barrier after its last reader. vmcnt(4) @P4
// completes prev-P7/P8 + this-P1/P2 (tile o resident before P5); @P8
// completes P3..P6 (tile e+2 resident before next P1). Final iteration stages
// nothing in P3..P8, so its P4 drains vmcnt(0) (tile o's A from P1/P2).
// ---------------------------------------------------------------------------
#define SBAR  do { __builtin_amdgcn_sched_barrier(0); __builtin_amdgcn_s_barrier(); \
                   __builtin_amdgcn_sched_barrier(0); } while (0)
#define LGKM0 do { asm volatile("s_waitcnt lgkmcnt(0)" ::: "memory"); \
                   __builtin_amdgcn_sched_barrier(0); } while (0)
#define LGKM8 do { asm volatile("s_waitcnt lgkmcnt(8)" ::: "memory"); } while (0)
#define VM4   do { asm volatile("s_waitcnt vmcnt(4)" ::: "memory"); } while (0)
#define VM0   do { asm volatile("s_waitcnt vmcnt(0)" ::: "memory"); } while (0)

__global__ __launch_bounds__(512, 2) void gemm256_bt(const unsigned short* __restrict__ A,
                                                     const unsigned short* __restrict__ Bt,
                                                     float* __restrict__ C,
                                                     int M, int N, int K) {
  __shared__ __attribute__((aligned(128))) unsigned short smem[2][4][8192];

  const int tid  = threadIdx.x;
  const int lane = tid & 63;
  const int wid  = tid >> 6;      // 0..7
  const int wr   = wid >> 2;      // 0..1  (M half owned by wave)
  const int wc   = wid & 3;       // 0..3  (N quarter owned by wave)
  const int la   = lane & 15;
  const int lq   = lane >> 4;
  const int sw   = la & 7;        // read-side swizzle key (row&7 == la&7)
  const int m0   = blockIdx.x * 256;
  const int n0   = blockIdx.y * 256;

  // staging decomposition: chunk = wid*2+is (1 KiB each), lane covers
  // physical (row = chunk*8 + (lane>>3), slot = lane&7); logical slot to
  // fetch = phys_slot ^ (row&7) = (lane&7) ^ (lane>>3).
  const int sr = lane >> 3;
  const int sl = (lane & 7) ^ sr;

  const unsigned short* gA[2][2];
  const unsigned short* gB[2][2];
#pragma unroll
  for (int h = 0; h < 2; ++h)
#pragma unroll
    for (int is = 0; is < 2; ++is) {
      int r = (wid * 2 + is) * 8 + sr;
      gA[h][is] = A  + (size_t)(m0 + h * 128 + r) * K + sl * 8;
      gB[h][is] = Bt + (size_t)(n0 + h * 128 + r) * K + sl * 8;
    }

#define STG_A(buf, h, kt) do { \
    async_cp16(gA[h][0] + (kt) * 64, &smem[buf][h][(wid * 2 + 0) * 512]); \
    async_cp16(gA[h][1] + (kt) * 64, &smem[buf][h][(wid * 2 + 1) * 512]); \
  } while (0)
#define STG_B(buf, h, kt) do { \
    async_cp16(gB[h][0] + (kt) * 64, &smem[buf][2 + (h)][(wid * 2 + 0) * 512]); \
    async_cp16(gB[h][1] + (kt) * 64, &smem[buf][2 + (h)][(wid * 2 + 1) * 512]); \
  } while (0)

  f32x4  acc[8][4] = {};
  bf16x8 ar[8], b0r[4], b1r[4];

#define RD_A(buf, qm) do { \
    const unsigned short* rp_ = &smem[buf][wr][0]; \
    _Pragma("unroll") \
    for (int i_ = 0; i_ < 4; ++i_) { \
      int ro_ = ((qm) * 64 + i_ * 16 + la) * 64; \
      ar[i_ * 2 + 0] = frag_ld(rp_ + ro_ + (((0 + lq) ^ sw) << 3)); \
      ar[i_ * 2 + 1] = frag_ld(rp_ + ro_ + (((4 + lq) ^ sw) << 3)); \
    } \
  } while (0)
#define RD_B(buf, qn, breg) do { \
    const unsigned short* rp_ = &smem[buf][2 + (wc >> 1)][0]; \
    _Pragma("unroll") \
    for (int j_ = 0; j_ < 2; ++j_) { \
      int ro_ = ((wc & 1) * 64 + (qn) * 32 + j_ * 16 + la) * 64; \
      breg[j_ * 2 + 0] = frag_ld(rp_ + ro_ + (((0 + lq) ^ sw) << 3)); \
      breg[j_ * 2 + 1] = frag_ld(rp_ + ro_ + (((4 + lq) ^ sw) << 3)); \
    } \
  } while (0)
#define MMA_Q(qm, qn, breg) do { \
    _Pragma("unroll") \
    for (int i_ = 0; i_ < 4; ++i_) \
      _Pragma("unroll") \
      for (int j_ = 0; j_ < 2; ++j_) { \
        f32x4 c_ = acc[(qm) * 4 + i_][(qn) * 2 + j_]; \
        c_ = mfma16(ar[i_ * 2 + 0], breg[j_ * 2 + 0], c_); \
        c_ = mfma16(ar[i_ * 2 + 1], breg[j_ * 2 + 1], c_); \
        acc[(qm) * 4 + i_][(qn) * 2 + j_] = c_; \
      } \
  } while (0)

  // prologue: tile0 -> buf0 fully; tile1 B halves -> buf1 (A halves arrive at
  // iter0 P1/P2 per the ledger).
  STG_A(0, 0, 0); STG_A(0, 1, 0);
  STG_B(0, 0, 0); STG_B(0, 1, 0);
  STG_B(1, 0, 1); STG_B(1, 1, 1);
  VM4;   // buf0's 8 loads landed; buf1.B's 4 may remain in flight
  SBAR;

  const int NI = K >> 7;   // iterations of 2 K-tiles (K multiple of 128)
  for (int it = 0; it < NI; ++it) {
    const int e = it * 2;
    const bool pf = (it + 1 < NI);
    // ---- P1
    RD_A(0, 0);
    RD_B(0, 0, b0r);
    STG_A(1, 0, e + 1);
    LGKM8;
    SBAR; LGKM0;
    __builtin_amdgcn_s_setprio(1); MMA_Q(0, 0, b0r); __builtin_amdgcn_s_setprio(0);
    SBAR;
    // ---- P2
    RD_B(0, 1, b1r);
    STG_A(1, 1, e + 1);
    SBAR; LGKM0;
    __builtin_amdgcn_s_setprio(1); MMA_Q(0, 1, b1r); __builtin_amdgcn_s_setprio(0);
    SBAR;
    // ---- P3
    RD_A(0, 1);
    if (pf) STG_B(0, 0, e + 2);
    SBAR; LGKM0;
    __builtin_amdgcn_s_setprio(1); MMA_Q(1, 1, b1r); __builtin_amdgcn_s_setprio(0);
    SBAR;
    // ---- P4
    if (pf) STG_B(0, 1, e + 2);
    SBAR; LGKM0;
    __builtin_amdgcn_s_setprio(1); MMA_Q(1, 0, b0r); __builtin_amdgcn_s_setprio(0);
    if (pf) { VM4; } else { VM0; }
    SBAR;
    // ---- P5
    RD_A(1, 0);
    RD_B(1, 0, b0r);
    if (pf) STG_A(0, 0, e + 2);
    LGKM8;
    SBAR; LGKM0;
    __builtin_amdgcn_s_setprio(1); MMA_Q(0, 0, b0r); __builtin_amdgcn_s_setprio(0);
    SBAR;
    // ---- P6
    RD_B(1, 1, b1r);
    if (pf) STG_A(0, 1, e + 2);
    SBAR; LGKM0;
    __builtin_amdgcn_s_setprio(1); MMA_Q(0, 1, b1r); __builtin_amdgcn_s_setprio(0);
    SBAR;
    // ---- P7
    RD_A(1, 1);
    if (pf) STG_B(1, 0, e + 3);
    SBAR; LGKM0;
    __builtin_amdgcn_s_setprio(1); MMA_Q(1, 1, b1r); __builtin_amdgcn_s_setprio(0);
    SBAR;
    // ---- P8
    if (pf) STG_B(1, 1, e + 3);
    SBAR; LGKM0;
    __builtin_amdgcn_s_setprio(1); MMA_Q(1, 0, b0r); __builtin_amdgcn_s_setprio(0);
    VM4;
    SBAR;
  }

  // epilogue: C[row, col], col = lane&15, row = (lane>>4)*4 + r within frag
#pragma unroll
  for (int mf = 0; mf < 8; ++mf) {
    int row = m0 + wr * 128 + mf * 16 + lq * 4;
#pragma unroll
    for (int nf = 0; nf < 4; ++nf) {
      int col = n0 + wc * 64 + nf * 16 + la;
#pragma unroll
      for (int r = 0; r < 4; ++r)
        C[(size_t)(row + r) * N + col] = acc[mf][nf][r];
    }
  }
}

// ---------------------------------------------------------------------------
// RoPE: read QKV fp32, write q_b (bf16 * CSC_, [B][NH][T][D]) and knew (fp32)
__global__ __launch_bounds__(256) void rope_kernel(const float* __restrict__ QKV,
                                                   const int* __restrict__ pos_ids,
                                                   unsigned short* __restrict__ q_b,
                                                   float* __restrict__ knew) {
  int idx = blockIdx.x * 256 + threadIdx.x;
  const int total = B_ * T_ * (NH_ + NKV_) * 32;
  if (idx >= total) return;
  int i = idx & 31;
  int tmp = idx >> 5;
  int hh = tmp % (NH_ + NKV_);
  int bt = tmp / (NH_ + NKV_);
  int t = bt & (T_ - 1);
  int b = bt >> 11;
  int pos = pos_ids[bt] + STEPS_;
  float inv = exp2f(-(float)i * (13.287712379549449f / 32.0f));
  float ang = (float)pos * inv;
  float sn, cs;
  sincosf(ang, &sn, &cs);
  const float* rowp = QKV + (size_t)bt * 3072;
  if (hh < NH_) {
    float x1 = rowp[hh * 64 + i];
    float x2 = rowp[hh * 64 + 32 + i];
    float y1 = (x1 * cs - x2 * sn) * CSC_;   // fold score scale into q
    float y2 = (x2 * cs + x1 * sn) * CSC_;
    size_t o = ((size_t)(b * NH_ + hh) * T_ + t) * HD_ + i;
    q_b[o] = f2bf(y1);
    q_b[o + 32] = f2bf(y2);
  } else {
    int kv = hh - NH_;
    float x1 = rowp[2048 + kv * 64 + i];
    float x2 = rowp[2048 + kv * 64 + 32 + i];
    float y1 = x1 * cs - x2 * sn;
    float y2 = x2 * cs + x1 * sn;
    size_t o = ((size_t)(b * NKV_ + kv) * T_ + t) * HD_ + i;
    knew[o] = y1;
    knew[o + 32] = y2;
  }
}

// ---------------------------------------------------------------------------
// Flash attention v2: 128 Q rows/block, 64-key tiles, double-buffered K/V via
// global_load_lds (XOR-swizzled through source-address permutation), ONE
// barrier per tile. Scores in exp2 domain (scale pre-folded into q).
__global__ __launch_bounds__(256, 3) void flash_kernel(const unsigned short* __restrict__ qb,
                                                       const unsigned short* __restrict__ k0b,
                                                       const unsigned short* __restrict__ v0t,
                                                       float* __restrict__ Of,
                                                       float* __restrict__ ml) {
  __shared__ unsigned short sK[2][64 * 64];
  __shared__ unsigned short sV[2][64 * 64];
  __shared__ unsigned short sP[4][16 * 72];

  const int tid = threadIdx.x;
  const int lane = tid & 63;
  const int wave = tid >> 6;
  const int la = lane & 15;
  const int lq = lane >> 4;
  const int swz = la & 7;

  const int id = blockIdx.x;
  const int bh = (id & 7) * 8 + ((id >> 3) & 7);
  const int qt = 15 - (id >> 6);

  const size_t bhs = (size_t)bh;
  const unsigned short* gK = k0b + bhs * T_ * HD_;
  const unsigned short* gV = v0t + bhs * HD_ * T_;

  const int rb0 = qt * 128 + wave * 32;
  const int ktd = rb0 >> 6;
  const int ktmax = 2 * qt + 1;

  bf16x8 aq[2][2];
#pragma unroll
  for (int f = 0; f < 2; f++) {
    const unsigned short* qp = qb + (bhs * T_ + rb0 + f * 16 + la) * HD_;
    aq[f][0] = frag_ld(qp + lq * 8);
    aq[f][1] = frag_ld(qp + 32 + lq * 8);
  }

  f32x4 o[2][4] = {};
  float m_r[2][4], l_r[2][4];
#pragma unroll
  for (int f = 0; f < 2; f++)
#pragma unroll
    for (int r = 0; r < 4; r++) { m_r[f][r] = -1e30f; l_r[f][r] = 0.0f; }

  const int lrow = lane >> 3;
  const int lcb = (lane & 7) ^ lrow;

  {
    unsigned short* kd = &sK[0][wave * 1024];
    unsigned short* vd = &sV[0][wave * 1024];
    async_cp16(gK + (size_t)(wave * 16 + lrow) * HD_ + lcb * 8, kd);
    async_cp16(gK + (size_t)(wave * 16 + 8 + lrow) * HD_ + lcb * 8, kd + 512);
    async_cp16(gV + (size_t)(wave * 16 + lrow) * T_ + lcb * 8, vd);
    async_cp16(gV + (size_t)(wave * 16 + 8 + lrow) * T_ + lcb * 8, vd + 512);
  }
  __syncthreads();

  int cur = 0;
  for (int kt = 0; kt <= ktmax; ++kt) {
    if (kt < ktmax) {
      const int nk = (kt + 1) * 64;
      unsigned short* kd = &sK[cur ^ 1][wave * 1024];
      unsigned short* vd = &sV[cur ^ 1][wave * 1024];
      async_cp16(gK + (size_t)(nk + wave * 16 + lrow) * HD_ + lcb * 8, kd);
      async_cp16(gK + (size_t)(nk + wave * 16 + 8 + lrow) * HD_ + lcb * 8, kd + 512);
      async_cp16(gV + (size_t)(wave * 16 + lrow) * T_ + nk + lcb * 8, vd);
      async_cp16(gV + (size_t)(wave * 16 + 8 + lrow) * T_ + nk + lcb * 8, vd + 512);
    }

    if (kt <= ktd) {
      const unsigned short* kb = &sK[cur][0];
      const unsigned short* vb = &sV[cur][0];

      bf16x8 bk0[4], bk1[4];
#pragma unroll
      for (int nb = 0; nb < 4; nb++) {
        const unsigned short* rp = kb + (nb * 16 + la) * 64;
        bk0[nb] = frag_ld(rp + ((lq ^ swz) << 3));
        bk1[nb] = frag_ld(rp + (((lq + 4) ^ swz) << 3));
      }
      f32x4 s[2][4];
#pragma unroll
      for (int f = 0; f < 2; f++)
#pragma unroll
        for (int nb = 0; nb < 4; nb++) {
          f32x4 z = {0.f, 0.f, 0.f, 0.f};
          z = mfma16(aq[f][0], bk0[nb], z);
          z = mfma16(aq[f][1], bk1[nb], z);
          s[f][nb] = z;
        }

      const bool diag = (kt == ktd);
#pragma unroll
      for (int f = 0; f < 2; f++) {
        if (diag) {
#pragma unroll
          for (int nb = 0; nb < 4; nb++) {
            int key = kt * 64 + nb * 16 + la;
#pragma unroll
            for (int r = 0; r < 4; r++) {
              int row = rb0 + f * 16 + lq * 4 + r;
              s[f][nb][r] = (key <= row) ? s[f][nb][r] : -1e30f;
            }
          }
        }
        float tmax[4];
#pragma unroll
        for (int r = 0; r < 4; r++)
          tmax[r] = fmaxf(fmaxf(s[f][0][r], s[f][1][r]), fmaxf(s[f][2][r], s[f][3][r]));
#pragma unroll
        for (int off = 1; off < 16; off <<= 1)
#pragma unroll
          for (int r = 0; r < 4; r++) tmax[r] = fmaxf(tmax[r], __shfl_xor(tmax[r], off));
        float al[4], ls[4] = {0.f, 0.f, 0.f, 0.f};
#pragma unroll
        for (int r = 0; r < 4; r++) {
          float mn = fmaxf(m_r[f][r], tmax[r]);
          al[r] = exp2f(m_r[f][r] - mn);
          m_r[f][r] = mn;
        }
#pragma unroll
        for (int nb = 0; nb < 4; nb++)
#pragma unroll
          for (int r = 0; r < 4; r++) {
            float p = exp2f(s[f][nb][r] - m_r[f][r]);
            s[f][nb][r] = p;
            ls[r] += p;
          }
#pragma unroll
        for (int off = 1; off < 16; off <<= 1)
#pragma unroll
          for (int r = 0; r < 4; r++) ls[r] += __shfl_xor(ls[r], off);
#pragma unroll
        for (int r = 0; r < 4; r++) l_r[f][r] = l_r[f][r] * al[r] + ls[r];
#pragma unroll
        for (int jd = 0; jd < 4; jd++)
#pragma unroll
          for (int r = 0; r < 4; r++) o[f][jd][r] *= al[r];
      }

      bf16x8 bv0[4], bv1[4];
#pragma unroll
      for (int jd = 0; jd < 4; jd++) {
        const unsigned short* rp = vb + (jd * 16 + la) * 64;
        bv0[jd] = frag_ld(rp + ((lq ^ swz) << 3));
        bv1[jd] = frag_ld(rp + (((lq + 4) ^ swz) << 3));
      }
      unsigned short* pw = &sP[wave][0];
#pragma unroll
      for (int f = 0; f < 2; f++) {
#pragma unroll
        for (int nb = 0; nb < 4; nb++)
#pragma unroll
          for (int r = 0; r < 4; r++)
            pw[(lq * 4 + r) * 72 + nb * 16 + la] = f2bf(s[f][nb][r]);
        bf16x8 ap0 = frag_ld(&pw[la * 72 + lq * 8]);
        bf16x8 ap1 = frag_ld(&pw[la * 72 + 32 + lq * 8]);
#pragma unroll
        for (int jd = 0; jd < 4; jd++) {
          o[f][jd] = mfma16(ap0, bv0[jd], o[f][jd]);
          o[f][jd] = mfma16(ap1, bv1[jd], o[f][jd]);
        }
      }
    }
    __syncthreads();
    cur ^= 1;
  }

#pragma unroll
  for (int f = 0; f < 2; f++)
#pragma unroll
    for (int jd = 0; jd < 4; jd++)
#pragma unroll
      for (int r = 0; r < 4; r++) {
        int row = rb0 + f * 16 + lq * 4 + r;
        Of[(bhs * T_ + row) * HD_ + jd * 16 + la] = o[f][jd][r];
      }
  if (la == 0) {
#pragma unroll
    for (int f = 0; f < 2; f++)
#pragma unroll
      for (int r = 0; r < 4; r++) {
        int row = rb0 + f * 16 + lq * 4 + r;
        ml[(bhs * T_ + row) * 2] = m_r[f][r];
        ml[(bhs * T_ + row) * 2 + 1] = l_r[f][r];
      }
  }
}

// ---------------------------------------------------------------------------
// Epilogue: fold the two diagonal keys (prev_k[1], new k) into the flash result.
__global__ __launch_bounds__(256) void attn_epilogue(const unsigned short* __restrict__ qb,
                                                     const float* __restrict__ prev_k,
                                                     const float* __restrict__ prev_v,
                                                     const float* __restrict__ knew,
                                                     const float* __restrict__ QKV,
                                                     const float* __restrict__ Of,
                                                     const float* __restrict__ ml,
                                                     unsigned short* __restrict__ attnout) {
  const int lane = threadIdx.x & 63;
  const int wave = threadIdx.x >> 6;
  const int row = blockIdx.x * 4 + wave;  // (b*NH+h)*T + t
  const int b = row >> 16;
  const int h = (row >> 11) & 31;
  const int t = row & 2047;
  const int d = lane;
  const size_t base = (size_t)row * HD_ + d;

  float q = bf2f(qb[base]);   // includes CSC_ factor
  const size_t p1i = ((size_t)B_ * NH_ * T_ * HD_) + (((size_t)b * NH_ + h) * T_ + t) * HD_ + d;
  float k1 = prev_k[p1i];
  float v1 = prev_v[p1i];
  int kv = h >> 2;
  float kn = knew[(((size_t)b * NKV_ + kv) * T_ + t) * HD_ + d];
  float vn = QKV[((size_t)(b * T_ + t)) * 3072 + 2560 + kv * 64 + d];

  float e1 = q * k1, e2 = q * kn;
#pragma unroll
  for (int off = 1; off < 64; off <<= 1) {
    e1 += __shfl_xor(e1, off);
    e2 += __shfl_xor(e2, off);
  }

  float m = ml[(size_t)row * 2];
  float l = ml[(size_t)row * 2 + 1];
  float mf = fmaxf(m, fmaxf(e1, e2));
  float w0 = exp2f(m - mf), w1 = exp2f(e1 - mf), w2 = exp2f(e2 - mf);
  float denom = l * w0 + w1 + w2;
  float out = (Of[base] * w0 + v1 * w1 + vn * w2) / denom;

  attnout[((size_t)(b * T_ + t)) * (NH_ * HD_) + h * HD_ + d] = f2bf(out);
}

// ---------------------------------------------------------------------------
// Workspace layout (bytes; needs ws_size >= 178,257,920)
#define OFF_QKV   ((size_t)0)
#define OFF_XB    ((size_t)50331648)
#define OFF_WQKVT ((size_t)83886080)
#define OFF_WOT   ((size_t)109051904)
#define OFF_QB    ((size_t)117440512)
#define OFF_K0B   ((size_t)134217728)
#define OFF_V0T   ((size_t)150994944)
#define OFF_KNEW  ((size_t)167772160)
#define OFF_ML    ((size_t)176160768)

extern "C" void kernel_launch(void* const* d_in, const int* in_sizes, int n_in,
                              void* d_out, int out_size, void* d_ws, size_t ws_size,
                              hipStream_t stream) {
  const float* X = (const float*)d_in[0];
  const int* pos = (const int*)d_in[2];
  const float* prevk = (const float*)d_in[3];
  const float* prevv = (const float*)d_in[4];
  const float* Wq = (const float*)d_in[5];
  const float* Wk = (const float*)d_in[6];
  const float* Wv = (const float*)d_in[7];
  const float* Wo = (const float*)d_in[8];

  char* ws = (char*)d_ws;
  float* QKV = (float*)(ws + OFF_QKV);
  unsigned short* Xb = (unsigned short*)(ws + OFF_XB);
  float* Of = (float*)(ws + OFF_XB);
  unsigned short* WqkvT = (unsigned short*)(ws + OFF_WQKVT);
  unsigned short* attnout = (unsigned short*)(ws + OFF_WQKVT);
  unsigned short* WoT = (unsigned short*)(ws + OFF_WOT);
  unsigned short* q_b = (unsigned short*)(ws + OFF_QB);
  unsigned short* k0b = (unsigned short*)(ws + OFF_K0B);
  unsigned short* v0t = (unsigned short*)(ws + OFF_V0T);
  float* knew = (float*)(ws + OFF_KNEW);
  float* ml = (float*)(ws + OFF_ML);

  convert_bf16<<<16384, 256, 0, stream>>>(X, Xb, 4194304);
  transpose_f32_bf16_ld<<<dim3(32, 64), 256, 0, stream>>>(Wq, WqkvT, 4096, 2048, 4096);
  transpose_f32_bf16_ld<<<dim3(8, 64), 256, 0, stream>>>(Wk, WqkvT + (size_t)2048 * 4096, 4096, 512, 4096);
  transpose_f32_bf16_ld<<<dim3(8, 64), 256, 0, stream>>>(Wv, WqkvT + (size_t)2560 * 4096, 4096, 512, 4096);
  transpose_f32_bf16_ld<<<dim3(32, 32), 256, 0, stream>>>(Wo, WoT, 2048, 2048, 2048);
  convert_bf16<<<8192, 256, 0, stream>>>(prevk, k0b, 2097152);
  transpose_v0<<<dim3(32, 64), 256, 0, stream>>>(prevv, v0t);

  gemm256_bt<<<dim3(16, 12), 512, 0, stream>>>(Xb, WqkvT, QKV, 4096, 3072, 4096);

  rope_kernel<<<20480, 256, 0, stream>>>(QKV, pos, q_b, knew);

  flash_kernel<<<1024, 256, 0, stream>>>(q_b, k0b, v0t, Of, ml);

  attn_epilogue<<<32768, 256, 0, stream>>>(q_b, prevk, prevv, knew, QKV, Of, ml, attnout);

  gemm256_bt<<<dim3(16, 8), 512, 0, stream>>>(attnout, WoT, (float*)d_out, 4096, 2048, 2048);
}

// Round 3
// 556.055 us; speedup vs baseline: 1.1378x; 1.0565x over previous
//
#include <hip/hip_runtime.h>

// Problem constants
#define B_    2
#define T_    2048
#define HID_  2048
#define NH_   32
#define NKV_  8
#define HD_   64
#define STEPS_ 2
#define SCALE_ 0.125f
// SCALE * log2(e): scores kept in exp2 domain throughout (folded into q at RoPE)
#define CSC_  0.18033688011112042f

typedef float   f32x4  __attribute__((ext_vector_type(4)));
typedef __bf16  bf16x8 __attribute__((ext_vector_type(8)));
typedef unsigned short u16x8 __attribute__((ext_vector_type(8)));

__device__ __forceinline__ unsigned short f2bf(float f) {
  unsigned int u = __builtin_bit_cast(unsigned int, f);
  u = (u + 0x7fffu + ((u >> 16) & 1u)) >> 16;
  return (unsigned short)u;
}
__device__ __forceinline__ float bf2f(unsigned short h) {
  unsigned int u = ((unsigned int)h) << 16;
  return __builtin_bit_cast(float, u);
}
__device__ __forceinline__ bf16x8 frag_ld(const unsigned short* p) {
  u16x8 v = *(const u16x8*)p;
  return __builtin_bit_cast(bf16x8, v);
}
__device__ __forceinline__ f32x4 mfma16(bf16x8 a, bf16x8 b, f32x4 c) {
  return __builtin_amdgcn_mfma_f32_16x16x32_bf16(a, b, c, 0, 0, 0);
}
__device__ __forceinline__ void async_cp16(const void* g, void* l) {
  __builtin_amdgcn_global_load_lds(
      (const __attribute__((address_space(1))) void*)g,
      (__attribute__((address_space(3))) void*)l, 16, 0, 0);
}
// HW packed f32->bf16 (RNE), no builtin on gfx950 -> inline asm (guide T12)
__device__ __forceinline__ unsigned int cvtpk_bf16(float lo, float hi) {
  unsigned int r;
  asm("v_cvt_pk_bf16_f32 %0, %1, %2" : "=v"(r) : "v"(lo), "v"(hi));
  return r;
}

// ---------------------------------------------------------------------------
// elementwise fp32 -> bf16 convert (float4 per thread)
__global__ __launch_bounds__(256) void convert_bf16(const float* __restrict__ in,
                                                    unsigned short* __restrict__ out,
                                                    int n4) {
  int idx = blockIdx.x * 256 + threadIdx.x;
  if (idx < n4) {
    float4 v = ((const float4*)in)[idx];
    ushort4 o;
    o.x = f2bf(v.x); o.y = f2bf(v.y); o.z = f2bf(v.z); o.w = f2bf(v.w);
    ((ushort4*)out)[idx] = o;
  }
}

// transpose + convert: in (K x N fp32 row-major) -> out (N x K bf16, ld=ldo)
__global__ __launch_bounds__(256) void transpose_f32_bf16_ld(const float* __restrict__ in,
                                                             unsigned short* __restrict__ out,
                                                             int K, int N, int ldo) {
  __shared__ float tile[64][65];
  int n0 = blockIdx.x * 64, k0 = blockIdx.y * 64;
  int c = threadIdx.x & 63, w = threadIdx.x >> 6;
#pragma unroll
  for (int i = 0; i < 16; i++) {
    int r = w * 16 + i;
    tile[r][c] = in[(size_t)(k0 + r) * N + n0 + c];
  }
  __syncthreads();
#pragma unroll
  for (int i = 0; i < 16; i++) {
    int rr = w * 16 + i;
    out[(size_t)(n0 + rr) * ldo + k0 + c] = f2bf(tile[c][rr]);
  }
}

// v0 (B*NH slabs of [T][D] fp32) -> v0t bf16 [B*NH][D][T]
__global__ __launch_bounds__(256) void transpose_v0(const float* __restrict__ v0,
                                                    unsigned short* __restrict__ v0t) {
  __shared__ float tile[64][65];
  int s0 = blockIdx.x * 64;
  int bh = blockIdx.y;
  const float* src = v0 + (size_t)bh * T_ * HD_;
  unsigned short* dst = v0t + (size_t)bh * HD_ * T_;
  int c = threadIdx.x & 63, w = threadIdx.x >> 6;
#pragma unroll
  for (int i = 0; i < 16; i++) {
    int r = w * 16 + i;
    tile[r][c] = src[(size_t)(s0 + r) * HD_ + c];
  }
  __syncthreads();
#pragma unroll
  for (int i = 0; i < 16; i++) {
    int rr = w * 16 + i;
    dst[(size_t)rr * T_ + s0 + c] = f2bf(tile[c][rr]);
  }
}

// ---------------------------------------------------------------------------
// 256x256 8-phase bf16 GEMM: C(MxN fp32) = A(MxK) * Bt(NxK)^T
// (unchanged from round 2 -- verified 8-phase counted-vmcnt template)
// ---------------------------------------------------------------------------
#define SBAR  do { __builtin_amdgcn_sched_barrier(0); __builtin_amdgcn_s_barrier(); \
                   __builtin_amdgcn_sched_barrier(0); } while (0)
#define LGKM0 do { asm volatile("s_waitcnt lgkmcnt(0)" ::: "memory"); \
                   __builtin_amdgcn_sched_barrier(0); } while (0)
#define LGKM8 do { asm volatile("s_waitcnt lgkmcnt(8)" ::: "memory"); } while (0)
#define VM4   do { asm volatile("s_waitcnt vmcnt(4)" ::: "memory"); } while (0)
#define VM0   do { asm volatile("s_waitcnt vmcnt(0)" ::: "memory"); } while (0)

__global__ __launch_bounds__(512, 2) void gemm256_bt(const unsigned short* __restrict__ A,
                                                     const unsigned short* __restrict__ Bt,
                                                     float* __restrict__ C,
                                                     int M, int N, int K) {
  __shared__ __attribute__((aligned(128))) unsigned short smem[2][4][8192];

  const int tid  = threadIdx.x;
  const int lane = tid & 63;
  const int wid  = tid >> 6;      // 0..7
  const int wr   = wid >> 2;      // 0..1  (M half owned by wave)
  const int wc   = wid & 3;       // 0..3  (N quarter owned by wave)
  const int la   = lane & 15;
  const int lq   = lane >> 4;
  const int sw   = la & 7;        // read-side swizzle key (row&7 == la&7)
  const int m0   = blockIdx.x * 256;
  const int n0   = blockIdx.y * 256;

  const int sr = lane >> 3;
  const int sl = (lane & 7) ^ sr;

  const unsigned short* gA[2][2];
  const unsigned short* gB[2][2];
#pragma unroll
  for (int h = 0; h < 2; ++h)
#pragma unroll
    for (int is = 0; is < 2; ++is) {
      int r = (wid * 2 + is) * 8 + sr;
      gA[h][is] = A  + (size_t)(m0 + h * 128 + r) * K + sl * 8;
      gB[h][is] = Bt + (size_t)(n0 + h * 128 + r) * K + sl * 8;
    }

#define STG_A(buf, h, kt) do { \
    async_cp16(gA[h][0] + (kt) * 64, &smem[buf][h][(wid * 2 + 0) * 512]); \
    async_cp16(gA[h][1] + (kt) * 64, &smem[buf][h][(wid * 2 + 1) * 512]); \
  } while (0)
#define STG_B(buf, h, kt) do { \
    async_cp16(gB[h][0] + (kt) * 64, &smem[buf][2 + (h)][(wid * 2 + 0) * 512]); \
    async_cp16(gB[h][1] + (kt) * 64, &smem[buf][2 + (h)][(wid * 2 + 1) * 512]); \
  } while (0)

  f32x4  acc[8][4] = {};
  bf16x8 ar[8], b0r[4], b1r[4];

#define RD_A(buf, qm) do { \
    const unsigned short* rp_ = &smem[buf][wr][0]; \
    _Pragma("unroll") \
    for (int i_ = 0; i_ < 4; ++i_) { \
      int ro_ = ((qm) * 64 + i_ * 16 + la) * 64; \
      ar[i_ * 2 + 0] = frag_ld(rp_ + ro_ + (((0 + lq) ^ sw) << 3)); \
      ar[i_ * 2 + 1] = frag_ld(rp_ + ro_ + (((4 + lq) ^ sw) << 3)); \
    } \
  } while (0)
#define RD_B(buf, qn, breg) do { \
    const unsigned short* rp_ = &smem[buf][2 + (wc >> 1)][0]; \
    _Pragma("unroll") \
    for (int j_ = 0; j_ < 2; ++j_) { \
      int ro_ = ((wc & 1) * 64 + (qn) * 32 + j_ * 16 + la) * 64; \
      breg[j_ * 2 + 0] = frag_ld(rp_ + ro_ + (((0 + lq) ^ sw) << 3)); \
      breg[j_ * 2 + 1] = frag_ld(rp_ + ro_ + (((4 + lq) ^ sw) << 3)); \
    } \
  } while (0)
#define MMA_Q(qm, qn, breg) do { \
    _Pragma("unroll") \
    for (int i_ = 0; i_ < 4; ++i_) \
      _Pragma("unroll") \
      for (int j_ = 0; j_ < 2; ++j_) { \
        f32x4 c_ = acc[(qm) * 4 + i_][(qn) * 2 + j_]; \
        c_ = mfma16(ar[i_ * 2 + 0], breg[j_ * 2 + 0], c_); \
        c_ = mfma16(ar[i_ * 2 + 1], breg[j_ * 2 + 1], c_); \
        acc[(qm) * 4 + i_][(qn) * 2 + j_] = c_; \
      } \
  } while (0)

  STG_A(0, 0, 0); STG_A(0, 1, 0);
  STG_B(0, 0, 0); STG_B(0, 1, 0);
  STG_B(1, 0, 1); STG_B(1, 1, 1);
  VM4;
  SBAR;

  const int NI = K >> 7;
  for (int it = 0; it < NI; ++it) {
    const int e = it * 2;
    const bool pf = (it + 1 < NI);
    // ---- P1
    RD_A(0, 0);
    RD_B(0, 0, b0r);
    STG_A(1, 0, e + 1);
    LGKM8;
    SBAR; LGKM0;
    __builtin_amdgcn_s_setprio(1); MMA_Q(0, 0, b0r); __builtin_amdgcn_s_setprio(0);
    SBAR;
    // ---- P2
    RD_B(0, 1, b1r);
    STG_A(1, 1, e + 1);
    SBAR; LGKM0;
    __builtin_amdgcn_s_setprio(1); MMA_Q(0, 1, b1r); __builtin_amdgcn_s_setprio(0);
    SBAR;
    // ---- P3
    RD_A(0, 1);
    if (pf) STG_B(0, 0, e + 2);
    SBAR; LGKM0;
    __builtin_amdgcn_s_setprio(1); MMA_Q(1, 1, b1r); __builtin_amdgcn_s_setprio(0);
    SBAR;
    // ---- P4
    if (pf) STG_B(0, 1, e + 2);
    SBAR; LGKM0;
    __builtin_amdgcn_s_setprio(1); MMA_Q(1, 0, b0r); __builtin_amdgcn_s_setprio(0);
    if (pf) { VM4; } else { VM0; }
    SBAR;
    // ---- P5
    RD_A(1, 0);
    RD_B(1, 0, b0r);
    if (pf) STG_A(0, 0, e + 2);
    LGKM8;
    SBAR; LGKM0;
    __builtin_amdgcn_s_setprio(1); MMA_Q(0, 0, b0r); __builtin_amdgcn_s_setprio(0);
    SBAR;
    // ---- P6
    RD_B(1, 1, b1r);
    if (pf) STG_A(0, 1, e + 2);
    SBAR; LGKM0;
    __builtin_amdgcn_s_setprio(1); MMA_Q(0, 1, b1r); __builtin_amdgcn_s_setprio(0);
    SBAR;
    // ---- P7
    RD_A(1, 1);
    if (pf) STG_B(1, 0, e + 3);
    SBAR; LGKM0;
    __builtin_amdgcn_s_setprio(1); MMA_Q(1, 1, b1r); __builtin_amdgcn_s_setprio(0);
    SBAR;
    // ---- P8
    if (pf) STG_B(1, 1, e + 3);
    SBAR; LGKM0;
    __builtin_amdgcn_s_setprio(1); MMA_Q(1, 0, b0r); __builtin_amdgcn_s_setprio(0);
    VM4;
    SBAR;
  }

#pragma unroll
  for (int mf = 0; mf < 8; ++mf) {
    int row = m0 + wr * 128 + mf * 16 + lq * 4;
#pragma unroll
    for (int nf = 0; nf < 4; ++nf) {
      int col = n0 + wc * 64 + nf * 16 + la;
#pragma unroll
      for (int r = 0; r < 4; ++r)
        C[(size_t)(row + r) * N + col] = acc[mf][nf][r];
    }
  }
}

// ---------------------------------------------------------------------------
// RoPE: read QKV fp32, write q_b (bf16 * CSC_, [B][NH][T][D]) and knew (fp32)
__global__ __launch_bounds__(256) void rope_kernel(const float* __restrict__ QKV,
                                                   const int* __restrict__ pos_ids,
                                                   unsigned short* __restrict__ q_b,
                                                   float* __restrict__ knew) {
  int idx = blockIdx.x * 256 + threadIdx.x;
  const int total = B_ * T_ * (NH_ + NKV_) * 32;
  if (idx >= total) return;
  int i = idx & 31;
  int tmp = idx >> 5;
  int hh = tmp % (NH_ + NKV_);
  int bt = tmp / (NH_ + NKV_);
  int t = bt & (T_ - 1);
  int b = bt >> 11;
  int pos = pos_ids[bt] + STEPS_;
  float inv = exp2f(-(float)i * (13.287712379549449f / 32.0f));
  float ang = (float)pos * inv;
  float sn, cs;
  sincosf(ang, &sn, &cs);
  const float* rowp = QKV + (size_t)bt * 3072;
  if (hh < NH_) {
    float x1 = rowp[hh * 64 + i];
    float x2 = rowp[hh * 64 + 32 + i];
    float y1 = (x1 * cs - x2 * sn) * CSC_;   // fold score scale into q
    float y2 = (x2 * cs + x1 * sn) * CSC_;
    size_t o = ((size_t)(b * NH_ + hh) * T_ + t) * HD_ + i;
    q_b[o] = f2bf(y1);
    q_b[o + 32] = f2bf(y2);
  } else {
    int kv = hh - NH_;
    float x1 = rowp[2048 + kv * 64 + i];
    float x2 = rowp[2048 + kv * 64 + 32 + i];
    float y1 = x1 * cs - x2 * sn;
    float y2 = x2 * cs + x1 * sn;
    size_t o = ((size_t)(b * NKV_ + kv) * T_ + t) * HD_ + i;
    knew[o] = y1;
    knew[o + 32] = y2;
  }
}

// ---------------------------------------------------------------------------
// Flash attention v2, SWAPPED-QK^T variant.
//
// QK^T computed as mfma(K_frag, Q_frag): the A/B fragment layouts of
// mfma_f32_16x16x32_bf16 are identical per-lane, so swapping args transposes
// S. Output: col(la) = q-row within frag f, reg/lq = key (nb*16 + lq*4 + r).
// => each lane owns 16 key-scores of ONE q-row: key-axis reduction is 15
// in-register ops + 2 shfl_xor (16/32) instead of 2x16 ds-permutes; softmax
// state m,l is one scalar/lane. Rescale factor al must cross to the O domain
// (qrow = lq*4+r there): 4 shfl, skipped entirely via defer-max (THR=8, T13)
// when no lane's tile-max exceeds m+8. P -> bf16 via v_cvt_pk_bf16_f32 (8
// instr vs 48 int-ops) + 4 ds_write_b64 into the per-wave sP row-major image;
// PV A-frag read back as before (per-wave LDS round trip, same-wave DS
// ordering guarantees, pattern already verified in this kernel).
__global__ __launch_bounds__(256, 3) void flash_kernel(const unsigned short* __restrict__ qb,
                                                       const unsigned short* __restrict__ k0b,
                                                       const unsigned short* __restrict__ v0t,
                                                       float* __restrict__ Of,
                                                       float* __restrict__ ml) {
  __shared__ unsigned short sK[2][64 * 64];
  __shared__ unsigned short sV[2][64 * 64];
  __shared__ unsigned short sP[4][16 * 72];

  const int tid = threadIdx.x;
  const int lane = tid & 63;
  const int wave = tid >> 6;
  const int la = lane & 15;
  const int lq = lane >> 4;
  const int swz = la & 7;

  const int id = blockIdx.x;
  const int bh = (id & 7) * 8 + ((id >> 3) & 7);
  const int qt = 15 - (id >> 6);

  const size_t bhs = (size_t)bh;
  const unsigned short* gK = k0b + bhs * T_ * HD_;
  const unsigned short* gV = v0t + bhs * HD_ * T_;

  const int rb0 = qt * 128 + wave * 32;
  const int ktd = rb0 >> 6;
  const int ktmax = 2 * qt + 1;

  bf16x8 aq[2][2];
#pragma unroll
  for (int f = 0; f < 2; f++) {
    const unsigned short* qp = qb + (bhs * T_ + rb0 + f * 16 + la) * HD_;
    aq[f][0] = frag_ld(qp + lq * 8);
    aq[f][1] = frag_ld(qp + 32 + lq * 8);
  }

  f32x4 o[2][4] = {};
  float m_f[2] = {-1e30f, -1e30f};
  float l_f[2] = {0.0f, 0.0f};

  const int lrow = lane >> 3;
  const int lcb = (lane & 7) ^ lrow;

  {
    unsigned short* kd = &sK[0][wave * 1024];
    unsigned short* vd = &sV[0][wave * 1024];
    async_cp16(gK + (size_t)(wave * 16 + lrow) * HD_ + lcb * 8, kd);
    async_cp16(gK + (size_t)(wave * 16 + 8 + lrow) * HD_ + lcb * 8, kd + 512);
    async_cp16(gV + (size_t)(wave * 16 + lrow) * T_ + lcb * 8, vd);
    async_cp16(gV + (size_t)(wave * 16 + 8 + lrow) * T_ + lcb * 8, vd + 512);
  }
  __syncthreads();

  int cur = 0;
  for (int kt = 0; kt <= ktmax; ++kt) {
    if (kt < ktmax) {
      const int nk = (kt + 1) * 64;
      unsigned short* kd = &sK[cur ^ 1][wave * 1024];
      unsigned short* vd = &sV[cur ^ 1][wave * 1024];
      async_cp16(gK + (size_t)(nk + wave * 16 + lrow) * HD_ + lcb * 8, kd);
      async_cp16(gK + (size_t)(nk + wave * 16 + 8 + lrow) * HD_ + lcb * 8, kd + 512);
      async_cp16(gV + (size_t)(wave * 16 + lrow) * T_ + nk + lcb * 8, vd);
      async_cp16(gV + (size_t)(wave * 16 + 8 + lrow) * T_ + nk + lcb * 8, vd + 512);
    }

    if (kt <= ktd) {
      const unsigned short* kb = &sK[cur][0];
      const unsigned short* vb = &sV[cur][0];

      bf16x8 bk0[4], bk1[4];
#pragma unroll
      for (int nb = 0; nb < 4; nb++) {
        const unsigned short* rp = kb + (nb * 16 + la) * 64;
        bk0[nb] = frag_ld(rp + ((lq ^ swz) << 3));
        bk1[nb] = frag_ld(rp + (((lq + 4) ^ swz) << 3));
      }
      // S^T = K * Q^T : lane la = q-row (frag f), key = nb*16 + lq*4 + r
      f32x4 s[2][4];
      __builtin_amdgcn_s_setprio(1);
#pragma unroll
      for (int f = 0; f < 2; f++)
#pragma unroll
        for (int nb = 0; nb < 4; nb++) {
          f32x4 z = {0.f, 0.f, 0.f, 0.f};
          z = mfma16(bk0[nb], aq[f][0], z);
          z = mfma16(bk1[nb], aq[f][1], z);
          s[f][nb] = z;
        }
      __builtin_amdgcn_s_setprio(0);

      const bool diag = (kt == ktd);
#pragma unroll
      for (int f = 0; f < 2; f++) {
        const int qrow = rb0 + f * 16 + la;
        if (diag) {
#pragma unroll
          for (int nb = 0; nb < 4; nb++)
#pragma unroll
            for (int r = 0; r < 4; r++) {
              int key = kt * 64 + nb * 16 + lq * 4 + r;
              s[f][nb][r] = (key <= qrow) ? s[f][nb][r] : -1e30f;
            }
        }
        // in-register max over this lane's 16 keys, then across lq groups
        float t0 = fmaxf(fmaxf(s[f][0][0], s[f][0][1]), fmaxf(s[f][0][2], s[f][0][3]));
        float t1 = fmaxf(fmaxf(s[f][1][0], s[f][1][1]), fmaxf(s[f][1][2], s[f][1][3]));
        float t2 = fmaxf(fmaxf(s[f][2][0], s[f][2][1]), fmaxf(s[f][2][2], s[f][2][3]));
        float t3 = fmaxf(fmaxf(s[f][3][0], s[f][3][1]), fmaxf(s[f][3][2], s[f][3][3]));
        float tm = fmaxf(fmaxf(t0, t1), fmaxf(t2, t3));
        tm = fmaxf(tm, __shfl_xor(tm, 16));
        tm = fmaxf(tm, __shfl_xor(tm, 32));
        // defer-max (T13): only rescale when some row's max grew past m+8
        const bool resc = __any(tm > m_f[f] + 8.0f);
        if (resc) {
          float mn = fmaxf(m_f[f], tm);
          float al = exp2f(m_f[f] - mn);
          m_f[f] = mn;
          l_f[f] *= al;
          // al lives on lane (la = qrow); O accumulator has qrow = lq*4+r
          float a0 = __shfl(al, lq * 4 + 0);
          float a1 = __shfl(al, lq * 4 + 1);
          float a2 = __shfl(al, lq * 4 + 2);
          float a3 = __shfl(al, lq * 4 + 3);
#pragma unroll
          for (int jd = 0; jd < 4; jd++) {
            o[f][jd][0] *= a0;
            o[f][jd][1] *= a1;
            o[f][jd][2] *= a2;
            o[f][jd][3] *= a3;
          }
        }
        float ls = 0.0f;
#pragma unroll
        for (int nb = 0; nb < 4; nb++)
#pragma unroll
          for (int r = 0; r < 4; r++) {
            float p = exp2f(s[f][nb][r] - m_f[f]);
            s[f][nb][r] = p;
            ls += p;
          }
        ls += __shfl_xor(ls, 16);
        ls += __shfl_xor(ls, 32);
        l_f[f] += ls;
      }

      bf16x8 bv0[4], bv1[4];
#pragma unroll
      for (int jd = 0; jd < 4; jd++) {
        const unsigned short* rp = vb + (jd * 16 + la) * 64;
        bv0[jd] = frag_ld(rp + ((lq ^ swz) << 3));
        bv1[jd] = frag_ld(rp + (((lq + 4) ^ swz) << 3));
      }
      unsigned short* pw = &sP[wave][0];
#pragma unroll
      for (int f = 0; f < 2; f++) {
#pragma unroll
        for (int nb = 0; nb < 4; nb++) {
          unsigned int p01 = cvtpk_bf16(s[f][nb][0], s[f][nb][1]);
          unsigned int p23 = cvtpk_bf16(s[f][nb][2], s[f][nb][3]);
          unsigned long long pq = ((unsigned long long)p23 << 32) | (unsigned long long)p01;
          *(unsigned long long*)(pw + la * 72 + nb * 16 + lq * 4) = pq;
        }
        bf16x8 ap0 = frag_ld(&pw[la * 72 + lq * 8]);
        bf16x8 ap1 = frag_ld(&pw[la * 72 + 32 + lq * 8]);
        __builtin_amdgcn_s_setprio(1);
#pragma unroll
        for (int jd = 0; jd < 4; jd++) {
          o[f][jd] = mfma16(ap0, bv0[jd], o[f][jd]);
          o[f][jd] = mfma16(ap1, bv1[jd], o[f][jd]);
        }
        __builtin_amdgcn_s_setprio(0);
      }
    }
    __syncthreads();
    cur ^= 1;
  }

#pragma unroll
  for (int f = 0; f < 2; f++)
#pragma unroll
    for (int jd = 0; jd < 4; jd++)
#pragma unroll
      for (int r = 0; r < 4; r++) {
        int row = rb0 + f * 16 + lq * 4 + r;
        Of[(bhs * T_ + row) * HD_ + jd * 16 + la] = o[f][jd][r];
      }
  if (lq == 0) {
#pragma unroll
    for (int f = 0; f < 2; f++) {
      int row = rb0 + f * 16 + la;
      ml[(bhs * T_ + row) * 2] = m_f[f];
      ml[(bhs * T_ + row) * 2 + 1] = l_f[f];
    }
  }
}

// ---------------------------------------------------------------------------
// Epilogue: fold the two diagonal keys (prev_k[1], new k) into the flash result.
__global__ __launch_bounds__(256) void attn_epilogue(const unsigned short* __restrict__ qb,
                                                     const float* __restrict__ prev_k,
                                                     const float* __restrict__ prev_v,
                                                     const float* __restrict__ knew,
                                                     const float* __restrict__ QKV,
                                                     const float* __restrict__ Of,
                                                     const float* __restrict__ ml,
                                                     unsigned short* __restrict__ attnout) {
  const int lane = threadIdx.x & 63;
  const int wave = threadIdx.x >> 6;
  const int row = blockIdx.x * 4 + wave;  // (b*NH+h)*T + t
  const int b = row >> 16;
  const int h = (row >> 11) & 31;
  const int t = row & 2047;
  const int d = lane;
  const size_t base = (size_t)row * HD_ + d;

  float q = bf2f(qb[base]);   // includes CSC_ factor
  const size_t p1i = ((size_t)B_ * NH_ * T_ * HD_) + (((size_t)b * NH_ + h) * T_ + t) * HD_ + d;
  float k1 = prev_k[p1i];
  float v1 = prev_v[p1i];
  int kv = h >> 2;
  float kn = knew[(((size_t)b * NKV_ + kv) * T_ + t) * HD_ + d];
  float vn = QKV[((size_t)(b * T_ + t)) * 3072 + 2560 + kv * 64 + d];

  float e1 = q * k1, e2 = q * kn;
#pragma unroll
  for (int off = 1; off < 64; off <<= 1) {
    e1 += __shfl_xor(e1, off);
    e2 += __shfl_xor(e2, off);
  }

  float m = ml[(size_t)row * 2];
  float l = ml[(size_t)row * 2 + 1];
  float mf = fmaxf(m, fmaxf(e1, e2));
  float w0 = exp2f(m - mf), w1 = exp2f(e1 - mf), w2 = exp2f(e2 - mf);
  float denom = l * w0 + w1 + w2;
  float out = (Of[base] * w0 + v1 * w1 + vn * w2) / denom;

  attnout[((size_t)(b * T_ + t)) * (NH_ * HD_) + h * HD_ + d] = f2bf(out);
}

// ---------------------------------------------------------------------------
// Workspace layout (bytes; needs ws_size >= 178,257,920)
#define OFF_QKV   ((size_t)0)
#define OFF_XB    ((size_t)50331648)
#define OFF_WQKVT ((size_t)83886080)
#define OFF_WOT   ((size_t)109051904)
#define OFF_QB    ((size_t)117440512)
#define OFF_K0B   ((size_t)134217728)
#define OFF_V0T   ((size_t)150994944)
#define OFF_KNEW  ((size_t)167772160)
#define OFF_ML    ((size_t)176160768)

extern "C" void kernel_launch(void* const* d_in, const int* in_sizes, int n_in,
                              void* d_out, int out_size, void* d_ws, size_t ws_size,
                              hipStream_t stream) {
  const float* X = (const float*)d_in[0];
  const int* pos = (const int*)d_in[2];
  const float* prevk = (const float*)d_in[3];
  const float* prevv = (const float*)d_in[4];
  const float* Wq = (const float*)d_in[5];
  const float* Wk = (const float*)d_in[6];
  const float* Wv = (const float*)d_in[7];
  const float* Wo = (const float*)d_in[8];

  char* ws = (char*)d_ws;
  float* QKV = (float*)(ws + OFF_QKV);
  unsigned short* Xb = (unsigned short*)(ws + OFF_XB);
  float* Of = (float*)(ws + OFF_XB);
  unsigned short* WqkvT = (unsigned short*)(ws + OFF_WQKVT);
  unsigned short* attnout = (unsigned short*)(ws + OFF_WQKVT);
  unsigned short* WoT = (unsigned short*)(ws + OFF_WOT);
  unsigned short* q_b = (unsigned short*)(ws + OFF_QB);
  unsigned short* k0b = (unsigned short*)(ws + OFF_K0B);
  unsigned short* v0t = (unsigned short*)(ws + OFF_V0T);
  float* knew = (float*)(ws + OFF_KNEW);
  float* ml = (float*)(ws + OFF_ML);

  convert_bf16<<<16384, 256, 0, stream>>>(X, Xb, 4194304);
  transpose_f32_bf16_ld<<<dim3(32, 64), 256, 0, stream>>>(Wq, WqkvT, 4096, 2048, 4096);
  transpose_f32_bf16_ld<<<dim3(8, 64), 256, 0, stream>>>(Wk, WqkvT + (size_t)2048 * 4096, 4096, 512, 4096);
  transpose_f32_bf16_ld<<<dim3(8, 64), 256, 0, stream>>>(Wv, WqkvT + (size_t)2560 * 4096, 4096, 512, 4096);
  transpose_f32_bf16_ld<<<dim3(32, 32), 256, 0, stream>>>(Wo, WoT, 2048, 2048, 2048);
  convert_bf16<<<8192, 256, 0, stream>>>(prevk, k0b, 2097152);
  transpose_v0<<<dim3(32, 64), 256, 0, stream>>>(prevv, v0t);

  gemm256_bt<<<dim3(16, 12), 512, 0, stream>>>(Xb, WqkvT, QKV, 4096, 3072, 4096);

  rope_kernel<<<20480, 256, 0, stream>>>(QKV, pos, q_b, knew);

  flash_kernel<<<1024, 256, 0, stream>>>(q_b, k0b, v0t, Of, ml);

  attn_epilogue<<<32768, 256, 0, stream>>>(q_b, prevk, prevv, knew, QKV, Of, ml, attnout);

  gemm256_bt<<<dim3(16, 8), 512, 0, stream>>>(attnout, WoT, (float*)d_out, 4096, 2048, 2048);
}

// Round 4
// 523.104 us; speedup vs baseline: 1.2095x; 1.0630x over previous
//
#include <hip/hip_runtime.h>

// Problem constants
#define B_    2
#define T_    2048
#define HID_  2048
#define NH_   32
#define NKV_  8
#define HD_   64
#define STEPS_ 2
#define SCALE_ 0.125f
// SCALE * log2(e): scores kept in exp2 domain throughout (folded into q at RoPE)
#define CSC_  0.18033688011112042f

typedef float   f32x4  __attribute__((ext_vector_type(4)));
typedef __bf16  bf16x8 __attribute__((ext_vector_type(8)));
typedef unsigned short u16x8 __attribute__((ext_vector_type(8)));

__device__ __forceinline__ unsigned short f2bf(float f) {
  unsigned int u = __builtin_bit_cast(unsigned int, f);
  u = (u + 0x7fffu + ((u >> 16) & 1u)) >> 16;
  return (unsigned short)u;
}
__device__ __forceinline__ float bf2f(unsigned short h) {
  unsigned int u = ((unsigned int)h) << 16;
  return __builtin_bit_cast(float, u);
}
__device__ __forceinline__ bf16x8 frag_ld(const unsigned short* p) {
  u16x8 v = *(const u16x8*)p;
  return __builtin_bit_cast(bf16x8, v);
}
__device__ __forceinline__ f32x4 mfma16(bf16x8 a, bf16x8 b, f32x4 c) {
  return __builtin_amdgcn_mfma_f32_16x16x32_bf16(a, b, c, 0, 0, 0);
}
__device__ __forceinline__ void async_cp16(const void* g, void* l) {
  __builtin_amdgcn_global_load_lds(
      (const __attribute__((address_space(1))) void*)g,
      (__attribute__((address_space(3))) void*)l, 16, 0, 0);
}
// HW packed f32->bf16 (RNE), no builtin on gfx950 -> inline asm (guide T12)
__device__ __forceinline__ unsigned int cvtpk_bf16(float lo, float hi) {
  unsigned int r;
  asm("v_cvt_pk_bf16_f32 %0, %1, %2" : "=v"(r) : "v"(lo), "v"(hi));
  return r;
}

// ---------------------------------------------------------------------------
// elementwise fp32 -> bf16 convert (float4 per thread)
__global__ __launch_bounds__(256) void convert_bf16(const float* __restrict__ in,
                                                    unsigned short* __restrict__ out,
                                                    int n4) {
  int idx = blockIdx.x * 256 + threadIdx.x;
  if (idx < n4) {
    float4 v = ((const float4*)in)[idx];
    ushort4 o;
    o.x = f2bf(v.x); o.y = f2bf(v.y); o.z = f2bf(v.z); o.w = f2bf(v.w);
    ((ushort4*)out)[idx] = o;
  }
}

// transpose + convert: in (K x N fp32 row-major) -> out (N x K bf16, ld=ldo)
__global__ __launch_bounds__(256) void transpose_f32_bf16_ld(const float* __restrict__ in,
                                                             unsigned short* __restrict__ out,
                                                             int K, int N, int ldo) {
  __shared__ float tile[64][65];
  int n0 = blockIdx.x * 64, k0 = blockIdx.y * 64;
  int c = threadIdx.x & 63, w = threadIdx.x >> 6;
#pragma unroll
  for (int i = 0; i < 16; i++) {
    int r = w * 16 + i;
    tile[r][c] = in[(size_t)(k0 + r) * N + n0 + c];
  }
  __syncthreads();
#pragma unroll
  for (int i = 0; i < 16; i++) {
    int rr = w * 16 + i;
    out[(size_t)(n0 + rr) * ldo + k0 + c] = f2bf(tile[c][rr]);
  }
}

// v0 (B*NH slabs of [T][D] fp32) -> v0t bf16 [B*NH][D][T]
__global__ __launch_bounds__(256) void transpose_v0(const float* __restrict__ v0,
                                                    unsigned short* __restrict__ v0t) {
  __shared__ float tile[64][65];
  int s0 = blockIdx.x * 64;
  int bh = blockIdx.y;
  const float* src = v0 + (size_t)bh * T_ * HD_;
  unsigned short* dst = v0t + (size_t)bh * HD_ * T_;
  int c = threadIdx.x & 63, w = threadIdx.x >> 6;
#pragma unroll
  for (int i = 0; i < 16; i++) {
    int r = w * 16 + i;
    tile[r][c] = src[(size_t)(s0 + r) * HD_ + c];
  }
  __syncthreads();
#pragma unroll
  for (int i = 0; i < 16; i++) {
    int rr = w * 16 + i;
    dst[(size_t)rr * T_ + s0 + c] = f2bf(tile[c][rr]);
  }
}

// ---------------------------------------------------------------------------
// 128 x (NF*64) 8-phase bf16 GEMM: C(MxN fp32) = A(MxK) * Bt(NxK)^T
//
// Full-machine re-tile of the proven 8-phase template. BM=128, BN=NF*64
// (NF=6 -> 384 for QKV grid 32x8=256; NF=4 -> 256 for Wo grid 32x8=256).
// 8 waves (2M x 4N); per-wave C = 64 x NF*16. BK=64, double-buffered.
// LDS/buf: A [128][64] + B [NF*64][64]; 128 KiB (NF=6) / 96 KiB (NF=4).
// Stage unit = 128 rows = 16 KiB = 2 async_cp16/thread. Units per K-tile:
// A + NF/2 B-units. Swizzle: 16B-slot s stored at s ^ (row&7), realized as
// linear LDS dest + inverse-permuted global source; readers apply same XOR.
//
// Slot schedule per iteration (tiles e=2it -> buf0, o=e+1 -> buf1):
//         NF=6                    NF=4
//  P1:    b1.A  (o)               b1.B0 (o)        | rd b0 qm0,qn0 | mma(0,0)
//  P2:    b1.B0 (o)               b1.B1 (o)        | rd b0 qn1     | mma(0,1)
//  P3:    b1.B1 (o)               --               | rd b0 qm1     | mma(1,1)
//  P4:    b0.A  (e+2)*            b0.A  (e+2)*     | mma(1,0), VM(pf?2:0)
//  P5:    b0.B0 (e+2)*            b0.B0 (e+2)*     | rd b1 qm0,qn0 | mma(0,0)
//  P6:    b0.B1 (e+2)*            b0.B1 (e+2)*     | rd b1 qn1     | mma(0,1)
//  P7:    b0.B2 (e+2)*            --               | rd b1 qm1     | mma(1,1)
//  P8:    b1.B2 (o'=e+3)*         b1.A  (o'=e+3)*  | mma(1,0), VM(2)
//  (* = if pf).  Tile o's remaining slot (B2 / A) comes from prev-P8
//  (prologue for it=0).
// vmcnt ledger (2 ops per slot, per thread):
//  - end P4: outstanding = prevP8 + P1 + P2 + P3 + P4 = 10 (NF6) / 8 (NF4);
//    vmcnt(2) leaves only P4's -> tile o fully resident before P5 reads.
//    Last iteration (no P4 stage): vmcnt(0) drains o's P1-P3 + prevP8.
//  - end P8: outstanding = P4..P8 slots = 10 (NF6) / 8 (NF4); vmcnt(2)
//    leaves only P8's -> tile e+2 fully resident before next-P1 reads.
// WAR audit (stage >= 2 barriers after region's last ds_read):
//  b0.A last read P3 -> staged P4 (after P3's LGKM0+barrier).  b0.B* last
//  read P2 (qn1 spans units) -> staged P5/P6/P7.  b1.A last read P7 ->
//  staged next-P1 (NF6) / this-P8 (NF4, after P7's barrier).  b1.B0/B1
//  last read P6 -> staged next-P1..P3.  b1.B2 last read P6 -> this-P8.
// ---------------------------------------------------------------------------
#define SBAR  do { __builtin_amdgcn_sched_barrier(0); __builtin_amdgcn_s_barrier(); \
                   __builtin_amdgcn_sched_barrier(0); } while (0)
#define LGKM0 do { asm volatile("s_waitcnt lgkmcnt(0)" ::: "memory"); \
                   __builtin_amdgcn_sched_barrier(0); } while (0)
#define VM2   do { asm volatile("s_waitcnt vmcnt(2)" ::: "memory"); } while (0)
#define VM0   do { asm volatile("s_waitcnt vmcnt(0)" ::: "memory"); } while (0)

template <int NF>
__global__ __launch_bounds__(512, 2) void gemm128_bt(const unsigned short* __restrict__ A,
                                                     const unsigned short* __restrict__ Bt,
                                                     float* __restrict__ C,
                                                     int M, int N, int K) {
  constexpr int NHF = NF / 2;             // B frags per qn group per wave
  constexpr int BROWS = 128 + NF * 64;    // rows staged per buffer
  __shared__ __attribute__((aligned(128))) unsigned short smem[2][BROWS * 64];

  const int tid  = threadIdx.x;
  const int lane = tid & 63;
  const int wid  = tid >> 6;      // 0..7
  const int wr   = wid >> 2;      // 0..1  (M half: 64 rows)
  const int wc   = wid & 3;       // 0..3  (N quarter: NF*16 cols)
  const int la   = lane & 15;
  const int lq   = lane >> 4;
  const int sw   = la & 7;        // read-side swizzle key (row&7 == la&7)
  const int m0   = blockIdx.x * 128;
  const int n0   = blockIdx.y * (NF * 64);

  // staging: chunk = wid*2+is (1 KiB, 8 rows); lane covers physical
  // (row = chunk*8 + (lane>>3), slot = lane&7); fetches logical slot
  // (lane&7)^(row&7) so the linear DMA image realizes the XOR swizzle.
  const int sr = lane >> 3;
  const int sl = (lane & 7) ^ sr;

  const unsigned short* gA[2];
  const unsigned short* gB[NHF][2];
#pragma unroll
  for (int is = 0; is < 2; ++is) {
    int r = (wid * 2 + is) * 8 + sr;
    gA[is] = A + (size_t)(m0 + r) * K + sl * 8;
#pragma unroll
    for (int u = 0; u < NHF; ++u)
      gB[u][is] = Bt + (size_t)(n0 + u * 128 + r) * K + sl * 8;
  }

#define G_STG_A(buf, kt) do { \
    async_cp16(gA[0] + (size_t)(kt) * 64, &smem[buf][(wid * 2 + 0) * 512]); \
    async_cp16(gA[1] + (size_t)(kt) * 64, &smem[buf][(wid * 2 + 1) * 512]); \
  } while (0)
#define G_STG_B(buf, u, kt) do { \
    async_cp16(gB[u][0] + (size_t)(kt) * 64, &smem[buf][(128 + (u) * 128) * 64 + (wid * 2 + 0) * 512]); \
    async_cp16(gB[u][1] + (size_t)(kt) * 64, &smem[buf][(128 + (u) * 128) * 64 + (wid * 2 + 1) * 512]); \
  } while (0)

  f32x4  acc[4][NF] = {};
  bf16x8 aR[2][2], b0r[NHF][2], b1r[NHF][2];

#define G_RD_A(buf, qm) do { \
    const unsigned short* rp_ = &smem[buf][0]; \
    _Pragma("unroll") \
    for (int i_ = 0; i_ < 2; ++i_) { \
      int ro_ = (wr * 64 + (qm) * 32 + i_ * 16 + la) * 64; \
      aR[i_][0] = frag_ld(rp_ + ro_ + (((0 + lq) ^ sw) << 3)); \
      aR[i_][1] = frag_ld(rp_ + ro_ + (((4 + lq) ^ sw) << 3)); \
    } \
  } while (0)
#define G_RD_B(buf, qn, breg) do { \
    const unsigned short* rp_ = &smem[buf][128 * 64]; \
    _Pragma("unroll") \
    for (int j_ = 0; j_ < NHF; ++j_) { \
      int ro_ = (wc * (NF * 16) + (qn) * (NF * 8) + j_ * 16 + la) * 64; \
      breg[j_][0] = frag_ld(rp_ + ro_ + (((0 + lq) ^ sw) << 3)); \
      breg[j_][1] = frag_ld(rp_ + ro_ + (((4 + lq) ^ sw) << 3)); \
    } \
  } while (0)
#define G_MMA(qm, qn, breg) do { \
    _Pragma("unroll") \
    for (int i_ = 0; i_ < 2; ++i_) \
      _Pragma("unroll") \
      for (int j_ = 0; j_ < NHF; ++j_) { \
        f32x4 c_ = acc[(qm) * 2 + i_][(qn) * NHF + j_]; \
        c_ = mfma16(aR[i_][0], breg[j_][0], c_); \
        c_ = mfma16(aR[i_][1], breg[j_][1], c_); \
        acc[(qm) * 2 + i_][(qn) * NHF + j_] = c_; \
      } \
  } while (0)

  // prologue: tile0 fully -> buf0; tile1's prev-P8-role slot -> buf1.
  G_STG_A(0, 0);
#pragma unroll
  for (int u = 0; u < NHF; ++u) G_STG_B(0, u, 0);
  if constexpr (NF == 6) G_STG_B(1, 2, 1); else G_STG_A(1, 1);
  VM2;   // tile0's slots landed; the buf1 slot may stay in flight
  SBAR;

  const int NI = K >> 7;   // iterations of 2 K-tiles (K multiple of 128)
  for (int it = 0; it < NI; ++it) {
    const int e = it * 2;
    const bool pf = (it + 1 < NI);
    // ---- P1
    G_RD_A(0, 0);
    G_RD_B(0, 0, b0r);
    if constexpr (NF == 6) G_STG_A(1, e + 1); else G_STG_B(1, 0, e + 1);
    SBAR; LGKM0;
    __builtin_amdgcn_s_setprio(1); G_MMA(0, 0, b0r); __builtin_amdgcn_s_setprio(0);
    SBAR;
    // ---- P2
    G_RD_B(0, 1, b1r);
    if constexpr (NF == 6) G_STG_B(1, 0, e + 1); else G_STG_B(1, 1, e + 1);
    SBAR; LGKM0;
    __builtin_amdgcn_s_setprio(1); G_MMA(0, 1, b1r); __builtin_amdgcn_s_setprio(0);
    SBAR;
    // ---- P3
    G_RD_A(0, 1);
    if constexpr (NF == 6) G_STG_B(1, 1, e + 1);
    SBAR; LGKM0;
    __builtin_amdgcn_s_setprio(1); G_MMA(1, 1, b1r); __builtin_amdgcn_s_setprio(0);
    SBAR;
    // ---- P4
    if (pf) G_STG_A(0, e + 2);
    SBAR; LGKM0;
    __builtin_amdgcn_s_setprio(1); G_MMA(1, 0, b0r); __builtin_amdgcn_s_setprio(0);
    if (pf) { VM2; } else { VM0; }
    SBAR;
    // ---- P5
    G_RD_A(1, 0);
    G_RD_B(1, 0, b0r);
    if (pf) G_STG_B(0, 0, e + 2);
    SBAR; LGKM0;
    __builtin_amdgcn_s_setprio(1); G_MMA(0, 0, b0r); __builtin_amdgcn_s_setprio(0);
    SBAR;
    // ---- P6
    G_RD_B(1, 1, b1r);
    if (pf) G_STG_B(0, 1, e + 2);
    SBAR; LGKM0;
    __builtin_amdgcn_s_setprio(1); G_MMA(0, 1, b1r); __builtin_amdgcn_s_setprio(0);
    SBAR;
    // ---- P7
    G_RD_A(1, 1);
    if constexpr (NF == 6) { if (pf) G_STG_B(0, 2, e + 2); }
    SBAR; LGKM0;
    __builtin_amdgcn_s_setprio(1); G_MMA(1, 1, b1r); __builtin_amdgcn_s_setprio(0);
    SBAR;
    // ---- P8
    if constexpr (NF == 6) { if (pf) G_STG_B(1, 2, e + 3); }
    else                   { if (pf) G_STG_A(1, e + 3); }
    SBAR; LGKM0;
    __builtin_amdgcn_s_setprio(1); G_MMA(1, 0, b0r); __builtin_amdgcn_s_setprio(0);
    VM2;
    SBAR;
  }

  // epilogue: C[row, col], col = frag col + la, row = lq*4 + r within frag
#pragma unroll
  for (int mf = 0; mf < 4; ++mf) {
    int row = m0 + wr * 64 + mf * 16 + lq * 4;
#pragma unroll
    for (int nf = 0; nf < NF; ++nf) {
      int col = n0 + wc * (NF * 16) + nf * 16 + la;
#pragma unroll
      for (int r = 0; r < 4; ++r)
        C[(size_t)(row + r) * N + col] = acc[mf][nf][r];
    }
  }
#undef G_STG_A
#undef G_STG_B
#undef G_RD_A
#undef G_RD_B
#undef G_MMA
}

// ---------------------------------------------------------------------------
// RoPE: read QKV fp32, write q_b (bf16 * CSC_, [B][NH][T][D]) and knew (fp32)
__global__ __launch_bounds__(256) void rope_kernel(const float* __restrict__ QKV,
                                                   const int* __restrict__ pos_ids,
                                                   unsigned short* __restrict__ q_b,
                                                   float* __restrict__ knew) {
  int idx = blockIdx.x * 256 + threadIdx.x;
  const int total = B_ * T_ * (NH_ + NKV_) * 32;
  if (idx >= total) return;
  int i = idx & 31;
  int tmp = idx >> 5;
  int hh = tmp % (NH_ + NKV_);
  int bt = tmp / (NH_ + NKV_);
  int t = bt & (T_ - 1);
  int b = bt >> 11;
  int pos = pos_ids[bt] + STEPS_;
  float inv = exp2f(-(float)i * (13.287712379549449f / 32.0f));
  float ang = (float)pos * inv;
  float sn, cs;
  sincosf(ang, &sn, &cs);
  const float* rowp = QKV + (size_t)bt * 3072;
  if (hh < NH_) {
    float x1 = rowp[hh * 64 + i];
    float x2 = rowp[hh * 64 + 32 + i];
    float y1 = (x1 * cs - x2 * sn) * CSC_;   // fold score scale into q
    float y2 = (x2 * cs + x1 * sn) * CSC_;
    size_t o = ((size_t)(b * NH_ + hh) * T_ + t) * HD_ + i;
    q_b[o] = f2bf(y1);
    q_b[o + 32] = f2bf(y2);
  } else {
    int kv = hh - NH_;
    float x1 = rowp[2048 + kv * 64 + i];
    float x2 = rowp[2048 + kv * 64 + 32 + i];
    float y1 = x1 * cs - x2 * sn;
    float y2 = x2 * cs + x1 * sn;
    size_t o = ((size_t)(b * NKV_ + kv) * T_ + t) * HD_ + i;
    knew[o] = y1;
    knew[o + 32] = y2;
  }
}

// ---------------------------------------------------------------------------
// Flash attention v2, swapped-QK^T (unchanged from round 3 -- verified)
__global__ __launch_bounds__(256, 3) void flash_kernel(const unsigned short* __restrict__ qb,
                                                       const unsigned short* __restrict__ k0b,
                                                       const unsigned short* __restrict__ v0t,
                                                       float* __restrict__ Of,
                                                       float* __restrict__ ml) {
  __shared__ unsigned short sK[2][64 * 64];
  __shared__ unsigned short sV[2][64 * 64];
  __shared__ unsigned short sP[4][16 * 72];

  const int tid = threadIdx.x;
  const int lane = tid & 63;
  const int wave = tid >> 6;
  const int la = lane & 15;
  const int lq = lane >> 4;
  const int swz = la & 7;

  const int id = blockIdx.x;
  const int bh = (id & 7) * 8 + ((id >> 3) & 7);
  const int qt = 15 - (id >> 6);

  const size_t bhs = (size_t)bh;
  const unsigned short* gK = k0b + bhs * T_ * HD_;
  const unsigned short* gV = v0t + bhs * HD_ * T_;

  const int rb0 = qt * 128 + wave * 32;
  const int ktd = rb0 >> 6;
  const int ktmax = 2 * qt + 1;

  bf16x8 aq[2][2];
#pragma unroll
  for (int f = 0; f < 2; f++) {
    const unsigned short* qp = qb + (bhs * T_ + rb0 + f * 16 + la) * HD_;
    aq[f][0] = frag_ld(qp + lq * 8);
    aq[f][1] = frag_ld(qp + 32 + lq * 8);
  }

  f32x4 o[2][4] = {};
  float m_f[2] = {-1e30f, -1e30f};
  float l_f[2] = {0.0f, 0.0f};

  const int lrow = lane >> 3;
  const int lcb = (lane & 7) ^ lrow;

  {
    unsigned short* kd = &sK[0][wave * 1024];
    unsigned short* vd = &sV[0][wave * 1024];
    async_cp16(gK + (size_t)(wave * 16 + lrow) * HD_ + lcb * 8, kd);
    async_cp16(gK + (size_t)(wave * 16 + 8 + lrow) * HD_ + lcb * 8, kd + 512);
    async_cp16(gV + (size_t)(wave * 16 + lrow) * T_ + lcb * 8, vd);
    async_cp16(gV + (size_t)(wave * 16 + 8 + lrow) * T_ + lcb * 8, vd + 512);
  }
  __syncthreads();

  int cur = 0;
  for (int kt = 0; kt <= ktmax; ++kt) {
    if (kt < ktmax) {
      const int nk = (kt + 1) * 64;
      unsigned short* kd = &sK[cur ^ 1][wave * 1024];
      unsigned short* vd = &sV[cur ^ 1][wave * 1024];
      async_cp16(gK + (size_t)(nk + wave * 16 + lrow) * HD_ + lcb * 8, kd);
      async_cp16(gK + (size_t)(nk + wave * 16 + 8 + lrow) * HD_ + lcb * 8, kd + 512);
      async_cp16(gV + (size_t)(wave * 16 + lrow) * T_ + nk + lcb * 8, vd);
      async_cp16(gV + (size_t)(wave * 16 + 8 + lrow) * T_ + nk + lcb * 8, vd + 512);
    }

    if (kt <= ktd) {
      const unsigned short* kb = &sK[cur][0];
      const unsigned short* vb = &sV[cur][0];

      bf16x8 bk0[4], bk1[4];
#pragma unroll
      for (int nb = 0; nb < 4; nb++) {
        const unsigned short* rp = kb + (nb * 16 + la) * 64;
        bk0[nb] = frag_ld(rp + ((lq ^ swz) << 3));
        bk1[nb] = frag_ld(rp + (((lq + 4) ^ swz) << 3));
      }
      // S^T = K * Q^T : lane la = q-row (frag f), key = nb*16 + lq*4 + r
      f32x4 s[2][4];
      __builtin_amdgcn_s_setprio(1);
#pragma unroll
      for (int f = 0; f < 2; f++)
#pragma unroll
        for (int nb = 0; nb < 4; nb++) {
          f32x4 z = {0.f, 0.f, 0.f, 0.f};
          z = mfma16(bk0[nb], aq[f][0], z);
          z = mfma16(bk1[nb], aq[f][1], z);
          s[f][nb] = z;
        }
      __builtin_amdgcn_s_setprio(0);

      const bool diag = (kt == ktd);
#pragma unroll
      for (int f = 0; f < 2; f++) {
        const int qrow = rb0 + f * 16 + la;
        if (diag) {
#pragma unroll
          for (int nb = 0; nb < 4; nb++)
#pragma unroll
            for (int r = 0; r < 4; r++) {
              int key = kt * 64 + nb * 16 + lq * 4 + r;
              s[f][nb][r] = (key <= qrow) ? s[f][nb][r] : -1e30f;
            }
        }
        // in-register max over this lane's 16 keys, then across lq groups
        float t0 = fmaxf(fmaxf(s[f][0][0], s[f][0][1]), fmaxf(s[f][0][2], s[f][0][3]));
        float t1 = fmaxf(fmaxf(s[f][1][0], s[f][1][1]), fmaxf(s[f][1][2], s[f][1][3]));
        float t2 = fmaxf(fmaxf(s[f][2][0], s[f][2][1]), fmaxf(s[f][2][2], s[f][2][3]));
        float t3 = fmaxf(fmaxf(s[f][3][0], s[f][3][1]), fmaxf(s[f][3][2], s[f][3][3]));
        float tm = fmaxf(fmaxf(t0, t1), fmaxf(t2, t3));
        tm = fmaxf(tm, __shfl_xor(tm, 16));
        tm = fmaxf(tm, __shfl_xor(tm, 32));
        // defer-max (T13): only rescale when some row's max grew past m+8
        const bool resc = __any(tm > m_f[f] + 8.0f);
        if (resc) {
          float mn = fmaxf(m_f[f], tm);
          float al = exp2f(m_f[f] - mn);
          m_f[f] = mn;
          l_f[f] *= al;
          // al lives on lane (la = qrow); O accumulator has qrow = lq*4+r
          float a0 = __shfl(al, lq * 4 + 0);
          float a1 = __shfl(al, lq * 4 + 1);
          float a2 = __shfl(al, lq * 4 + 2);
          float a3 = __shfl(al, lq * 4 + 3);
#pragma unroll
          for (int jd = 0; jd < 4; jd++) {
            o[f][jd][0] *= a0;
            o[f][jd][1] *= a1;
            o[f][jd][2] *= a2;
            o[f][jd][3] *= a3;
          }
        }
        float ls = 0.0f;
#pragma unroll
        for (int nb = 0; nb < 4; nb++)
#pragma unroll
          for (int r = 0; r < 4; r++) {
            float p = exp2f(s[f][nb][r] - m_f[f]);
            s[f][nb][r] = p;
            ls += p;
          }
        ls += __shfl_xor(ls, 16);
        ls += __shfl_xor(ls, 32);
        l_f[f] += ls;
      }

      bf16x8 bv0[4], bv1[4];
#pragma unroll
      for (int jd = 0; jd < 4; jd++) {
        const unsigned short* rp = vb + (jd * 16 + la) * 64;
        bv0[jd] = frag_ld(rp + ((lq ^ swz) << 3));
        bv1[jd] = frag_ld(rp + (((lq + 4) ^ swz) << 3));
      }
      unsigned short* pw = &sP[wave][0];
#pragma unroll
      for (int f = 0; f < 2; f++) {
#pragma unroll
        for (int nb = 0; nb < 4; nb++) {
          unsigned int p01 = cvtpk_bf16(s[f][nb][0], s[f][nb][1]);
          unsigned int p23 = cvtpk_bf16(s[f][nb][2], s[f][nb][3]);
          unsigned long long pq = ((unsigned long long)p23 << 32) | (unsigned long long)p01;
          *(unsigned long long*)(pw + la * 72 + nb * 16 + lq * 4) = pq;
        }
        bf16x8 ap0 = frag_ld(&pw[la * 72 + lq * 8]);
        bf16x8 ap1 = frag_ld(&pw[la * 72 + 32 + lq * 8]);
        __builtin_amdgcn_s_setprio(1);
#pragma unroll
        for (int jd = 0; jd < 4; jd++) {
          o[f][jd] = mfma16(ap0, bv0[jd], o[f][jd]);
          o[f][jd] = mfma16(ap1, bv1[jd], o[f][jd]);
        }
        __builtin_amdgcn_s_setprio(0);
      }
    }
    __syncthreads();
    cur ^= 1;
  }

#pragma unroll
  for (int f = 0; f < 2; f++)
#pragma unroll
    for (int jd = 0; jd < 4; jd++)
#pragma unroll
      for (int r = 0; r < 4; r++) {
        int row = rb0 + f * 16 + lq * 4 + r;
        Of[(bhs * T_ + row) * HD_ + jd * 16 + la] = o[f][jd][r];
      }
  if (lq == 0) {
#pragma unroll
    for (int f = 0; f < 2; f++) {
      int row = rb0 + f * 16 + la;
      ml[(bhs * T_ + row) * 2] = m_f[f];
      ml[(bhs * T_ + row) * 2 + 1] = l_f[f];
    }
  }
}

// ---------------------------------------------------------------------------
// Epilogue: fold the two diagonal keys (prev_k[1], new k) into the flash result.
__global__ __launch_bounds__(256) void attn_epilogue(const unsigned short* __restrict__ qb,
                                                     const float* __restrict__ prev_k,
                                                     const float* __restrict__ prev_v,
                                                     const float* __restrict__ knew,
                                                     const float* __restrict__ QKV,
                                                     const float* __restrict__ Of,
                                                     const float* __restrict__ ml,
                                                     unsigned short* __restrict__ attnout) {
  const int lane = threadIdx.x & 63;
  const int wave = threadIdx.x >> 6;
  const int row = blockIdx.x * 4 + wave;  // (b*NH+h)*T + t
  const int b = row >> 16;
  const int h = (row >> 11) & 31;
  const int t = row & 2047;
  const int d = lane;
  const size_t base = (size_t)row * HD_ + d;

  float q = bf2f(qb[base]);   // includes CSC_ factor
  const size_t p1i = ((size_t)B_ * NH_ * T_ * HD_) + (((size_t)b * NH_ + h) * T_ + t) * HD_ + d;
  float k1 = prev_k[p1i];
  float v1 = prev_v[p1i];
  int kv = h >> 2;
  float kn = knew[(((size_t)b * NKV_ + kv) * T_ + t) * HD_ + d];
  float vn = QKV[((size_t)(b * T_ + t)) * 3072 + 2560 + kv * 64 + d];

  float e1 = q * k1, e2 = q * kn;
#pragma unroll
  for (int off = 1; off < 64; off <<= 1) {
    e1 += __shfl_xor(e1, off);
    e2 += __shfl_xor(e2, off);
  }

  float m = ml[(size_t)row * 2];
  float l = ml[(size_t)row * 2 + 1];
  float mf = fmaxf(m, fmaxf(e1, e2));
  float w0 = exp2f(m - mf), w1 = exp2f(e1 - mf), w2 = exp2f(e2 - mf);
  float denom = l * w0 + w1 + w2;
  float out = (Of[base] * w0 + v1 * w1 + vn * w2) / denom;

  attnout[((size_t)(b * T_ + t)) * (NH_ * HD_) + h * HD_ + d] = f2bf(out);
}

// ---------------------------------------------------------------------------
// Workspace layout (bytes; needs ws_size >= 178,257,920)
#define OFF_QKV   ((size_t)0)
#define OFF_XB    ((size_t)50331648)
#define OFF_WQKVT ((size_t)83886080)
#define OFF_WOT   ((size_t)109051904)
#define OFF_QB    ((size_t)117440512)
#define OFF_K0B   ((size_t)134217728)
#define OFF_V0T   ((size_t)150994944)
#define OFF_KNEW  ((size_t)167772160)
#define OFF_ML    ((size_t)176160768)

extern "C" void kernel_launch(void* const* d_in, const int* in_sizes, int n_in,
                              void* d_out, int out_size, void* d_ws, size_t ws_size,
                              hipStream_t stream) {
  const float* X = (const float*)d_in[0];
  const int* pos = (const int*)d_in[2];
  const float* prevk = (const float*)d_in[3];
  const float* prevv = (const float*)d_in[4];
  const float* Wq = (const float*)d_in[5];
  const float* Wk = (const float*)d_in[6];
  const float* Wv = (const float*)d_in[7];
  const float* Wo = (const float*)d_in[8];

  char* ws = (char*)d_ws;
  float* QKV = (float*)(ws + OFF_QKV);
  unsigned short* Xb = (unsigned short*)(ws + OFF_XB);
  float* Of = (float*)(ws + OFF_XB);
  unsigned short* WqkvT = (unsigned short*)(ws + OFF_WQKVT);
  unsigned short* attnout = (unsigned short*)(ws + OFF_WQKVT);
  unsigned short* WoT = (unsigned short*)(ws + OFF_WOT);
  unsigned short* q_b = (unsigned short*)(ws + OFF_QB);
  unsigned short* k0b = (unsigned short*)(ws + OFF_K0B);
  unsigned short* v0t = (unsigned short*)(ws + OFF_V0T);
  float* knew = (float*)(ws + OFF_KNEW);
  float* ml = (float*)(ws + OFF_ML);

  convert_bf16<<<16384, 256, 0, stream>>>(X, Xb, 4194304);
  transpose_f32_bf16_ld<<<dim3(32, 64), 256, 0, stream>>>(Wq, WqkvT, 4096, 2048, 4096);
  transpose_f32_bf16_ld<<<dim3(8, 64), 256, 0, stream>>>(Wk, WqkvT + (size_t)2048 * 4096, 4096, 512, 4096);
  transpose_f32_bf16_ld<<<dim3(8, 64), 256, 0, stream>>>(Wv, WqkvT + (size_t)2560 * 4096, 4096, 512, 4096);
  transpose_f32_bf16_ld<<<dim3(32, 32), 256, 0, stream>>>(Wo, WoT, 2048, 2048, 2048);
  convert_bf16<<<8192, 256, 0, stream>>>(prevk, k0b, 2097152);
  transpose_v0<<<dim3(32, 64), 256, 0, stream>>>(prevv, v0t);

  // QKV GEMM: M=4096, N=3072, K=4096; BM=128, BN=384 -> grid 32x8 = 256
  gemm128_bt<6><<<dim3(32, 8), 512, 0, stream>>>(Xb, WqkvT, QKV, 4096, 3072, 4096);

  rope_kernel<<<20480, 256, 0, stream>>>(QKV, pos, q_b, knew);

  flash_kernel<<<1024, 256, 0, stream>>>(q_b, k0b, v0t, Of, ml);

  attn_epilogue<<<32768, 256, 0, stream>>>(q_b, prevk, prevv, knew, QKV, Of, ml, attnout);

  // Wo GEMM: M=4096, N=2048, K=2048; BM=128, BN=256 -> grid 32x8 = 256
  gemm128_bt<4><<<dim3(32, 8), 512, 0, stream>>>(attnout, WoT, (float*)d_out, 4096, 2048, 2048);
}

// Round 5
// 518.014 us; speedup vs baseline: 1.2214x; 1.0098x over previous
//
#include <hip/hip_runtime.h>

// Problem constants
#define B_    2
#define T_    2048
#define HID_  2048
#define NH_   32
#define NKV_  8
#define HD_   64
#define STEPS_ 2
#define SCALE_ 0.125f
// SCALE * log2(e): scores kept in exp2 domain throughout (folded into q at RoPE)
#define CSC_  0.18033688011112042f

typedef float   f32x4  __attribute__((ext_vector_type(4)));
typedef __bf16  bf16x8 __attribute__((ext_vector_type(8)));
typedef unsigned short u16x8 __attribute__((ext_vector_type(8)));

__device__ __forceinline__ unsigned short f2bf(float f) {
  unsigned int u = __builtin_bit_cast(unsigned int, f);
  u = (u + 0x7fffu + ((u >> 16) & 1u)) >> 16;
  return (unsigned short)u;
}
__device__ __forceinline__ float bf2f(unsigned short h) {
  unsigned int u = ((unsigned int)h) << 16;
  return __builtin_bit_cast(float, u);
}
__device__ __forceinline__ bf16x8 frag_ld(const unsigned short* p) {
  u16x8 v = *(const u16x8*)p;
  return __builtin_bit_cast(bf16x8, v);
}
__device__ __forceinline__ f32x4 mfma16(bf16x8 a, bf16x8 b, f32x4 c) {
  return __builtin_amdgcn_mfma_f32_16x16x32_bf16(a, b, c, 0, 0, 0);
}
__device__ __forceinline__ void async_cp16(const void* g, void* l) {
  __builtin_amdgcn_global_load_lds(
      (const __attribute__((address_space(1))) void*)g,
      (__attribute__((address_space(3))) void*)l, 16, 0, 0);
}
// HW packed f32->bf16 (RNE), no builtin on gfx950 -> inline asm (guide T12)
__device__ __forceinline__ unsigned int cvtpk_bf16(float lo, float hi) {
  unsigned int r;
  asm("v_cvt_pk_bf16_f32 %0, %1, %2" : "=v"(r) : "v"(lo), "v"(hi));
  return r;
}

// ---------------------------------------------------------------------------
// elementwise fp32 -> bf16 convert (float4 per thread)
__global__ __launch_bounds__(256) void convert_bf16(const float* __restrict__ in,
                                                    unsigned short* __restrict__ out,
                                                    int n4) {
  int idx = blockIdx.x * 256 + threadIdx.x;
  if (idx < n4) {
    float4 v = ((const float4*)in)[idx];
    ushort4 o;
    o.x = f2bf(v.x); o.y = f2bf(v.y); o.z = f2bf(v.z); o.w = f2bf(v.w);
    ((ushort4*)out)[idx] = o;
  }
}

// transpose + convert: in (K x N fp32 row-major) -> out (N x K bf16, ld=ldo)
__global__ __launch_bounds__(256) void transpose_f32_bf16_ld(const float* __restrict__ in,
                                                             unsigned short* __restrict__ out,
                                                             int K, int N, int ldo) {
  __shared__ float tile[64][65];
  int n0 = blockIdx.x * 64, k0 = blockIdx.y * 64;
  int c = threadIdx.x & 63, w = threadIdx.x >> 6;
#pragma unroll
  for (int i = 0; i < 16; i++) {
    int r = w * 16 + i;
    tile[r][c] = in[(size_t)(k0 + r) * N + n0 + c];
  }
  __syncthreads();
#pragma unroll
  for (int i = 0; i < 16; i++) {
    int rr = w * 16 + i;
    out[(size_t)(n0 + rr) * ldo + k0 + c] = f2bf(tile[c][rr]);
  }
}

// v0 (B*NH slabs of [T][D] fp32) -> v0t bf16 [B*NH][D][T]
__global__ __launch_bounds__(256) void transpose_v0(const float* __restrict__ v0,
                                                    unsigned short* __restrict__ v0t) {
  __shared__ float tile[64][65];
  int s0 = blockIdx.x * 64;
  int bh = blockIdx.y;
  const float* src = v0 + (size_t)bh * T_ * HD_;
  unsigned short* dst = v0t + (size_t)bh * HD_ * T_;
  int c = threadIdx.x & 63, w = threadIdx.x >> 6;
#pragma unroll
  for (int i = 0; i < 16; i++) {
    int r = w * 16 + i;
    tile[r][c] = src[(size_t)(s0 + r) * HD_ + c];
  }
  __syncthreads();
#pragma unroll
  for (int i = 0; i < 16; i++) {
    int rr = w * 16 + i;
    dst[(size_t)rr * T_ + s0 + c] = f2bf(tile[c][rr]);
  }
}

// ---------------------------------------------------------------------------
// 128 x (NF*64) 8-phase bf16 GEMM: C(MxN fp32) = A(MxK) * Bt(NxK)^T
// (unchanged from round 4 -- verified; see that round's ledger comments)
// ---------------------------------------------------------------------------
#define SBAR  do { __builtin_amdgcn_sched_barrier(0); __builtin_amdgcn_s_barrier(); \
                   __builtin_amdgcn_sched_barrier(0); } while (0)
#define LGKM0 do { asm volatile("s_waitcnt lgkmcnt(0)" ::: "memory"); \
                   __builtin_amdgcn_sched_barrier(0); } while (0)
#define VM2   do { asm volatile("s_waitcnt vmcnt(2)" ::: "memory"); } while (0)
#define VM0   do { asm volatile("s_waitcnt vmcnt(0)" ::: "memory"); } while (0)

template <int NF>
__global__ __launch_bounds__(512, 2) void gemm128_bt(const unsigned short* __restrict__ A,
                                                     const unsigned short* __restrict__ Bt,
                                                     float* __restrict__ C,
                                                     int M, int N, int K) {
  constexpr int NHF = NF / 2;             // B frags per qn group per wave
  constexpr int BROWS = 128 + NF * 64;    // rows staged per buffer
  __shared__ __attribute__((aligned(128))) unsigned short smem[2][BROWS * 64];

  const int tid  = threadIdx.x;
  const int lane = tid & 63;
  const int wid  = tid >> 6;      // 0..7
  const int wr   = wid >> 2;      // 0..1  (M half: 64 rows)
  const int wc   = wid & 3;       // 0..3  (N quarter: NF*16 cols)
  const int la   = lane & 15;
  const int lq   = lane >> 4;
  const int sw   = la & 7;        // read-side swizzle key (row&7 == la&7)
  const int m0   = blockIdx.x * 128;
  const int n0   = blockIdx.y * (NF * 64);

  // staging: chunk = wid*2+is (1 KiB, 8 rows); lane covers physical
  // (row = chunk*8 + (lane>>3), slot = lane&7); fetches logical slot
  // (lane&7)^(row&7) so the linear DMA image realizes the XOR swizzle.
  const int sr = lane >> 3;
  const int sl = (lane & 7) ^ sr;

  const unsigned short* gA[2];
  const unsigned short* gB[NHF][2];
#pragma unroll
  for (int is = 0; is < 2; ++is) {
    int r = (wid * 2 + is) * 8 + sr;
    gA[is] = A + (size_t)(m0 + r) * K + sl * 8;
#pragma unroll
    for (int u = 0; u < NHF; ++u)
      gB[u][is] = Bt + (size_t)(n0 + u * 128 + r) * K + sl * 8;
  }

#define G_STG_A(buf, kt) do { \
    async_cp16(gA[0] + (size_t)(kt) * 64, &smem[buf][(wid * 2 + 0) * 512]); \
    async_cp16(gA[1] + (size_t)(kt) * 64, &smem[buf][(wid * 2 + 1) * 512]); \
  } while (0)
#define G_STG_B(buf, u, kt) do { \
    async_cp16(gB[u][0] + (size_t)(kt) * 64, &smem[buf][(128 + (u) * 128) * 64 + (wid * 2 + 0) * 512]); \
    async_cp16(gB[u][1] + (size_t)(kt) * 64, &smem[buf][(128 + (u) * 128) * 64 + (wid * 2 + 1) * 512]); \
  } while (0)

  f32x4  acc[4][NF] = {};
  bf16x8 aR[2][2], b0r[NHF][2], b1r[NHF][2];

#define G_RD_A(buf, qm) do { \
    const unsigned short* rp_ = &smem[buf][0]; \
    _Pragma("unroll") \
    for (int i_ = 0; i_ < 2; ++i_) { \
      int ro_ = (wr * 64 + (qm) * 32 + i_ * 16 + la) * 64; \
      aR[i_][0] = frag_ld(rp_ + ro_ + (((0 + lq) ^ sw) << 3)); \
      aR[i_][1] = frag_ld(rp_ + ro_ + (((4 + lq) ^ sw) << 3)); \
    } \
  } while (0)
#define G_RD_B(buf, qn, breg) do { \
    const unsigned short* rp_ = &smem[buf][128 * 64]; \
    _Pragma("unroll") \
    for (int j_ = 0; j_ < NHF; ++j_) { \
      int ro_ = (wc * (NF * 16) + (qn) * (NF * 8) + j_ * 16 + la) * 64; \
      breg[j_][0] = frag_ld(rp_ + ro_ + (((0 + lq) ^ sw) << 3)); \
      breg[j_][1] = frag_ld(rp_ + ro_ + (((4 + lq) ^ sw) << 3)); \
    } \
  } while (0)
#define G_MMA(qm, qn, breg) do { \
    _Pragma("unroll") \
    for (int i_ = 0; i_ < 2; ++i_) \
      _Pragma("unroll") \
      for (int j_ = 0; j_ < NHF; ++j_) { \
        f32x4 c_ = acc[(qm) * 2 + i_][(qn) * NHF + j_]; \
        c_ = mfma16(aR[i_][0], breg[j_][0], c_); \
        c_ = mfma16(aR[i_][1], breg[j_][1], c_); \
        acc[(qm) * 2 + i_][(qn) * NHF + j_] = c_; \
      } \
  } while (0)

  // prologue: tile0 fully -> buf0; tile1's prev-P8-role slot -> buf1.
  G_STG_A(0, 0);
#pragma unroll
  for (int u = 0; u < NHF; ++u) G_STG_B(0, u, 0);
  if constexpr (NF == 6) G_STG_B(1, 2, 1); else G_STG_A(1, 1);
  VM2;   // tile0's slots landed; the buf1 slot may stay in flight
  SBAR;

  const int NI = K >> 7;   // iterations of 2 K-tiles (K multiple of 128)
  for (int it = 0; it < NI; ++it) {
    const int e = it * 2;
    const bool pf = (it + 1 < NI);
    // ---- P1
    G_RD_A(0, 0);
    G_RD_B(0, 0, b0r);
    if constexpr (NF == 6) G_STG_A(1, e + 1); else G_STG_B(1, 0, e + 1);
    SBAR; LGKM0;
    __builtin_amdgcn_s_setprio(1); G_MMA(0, 0, b0r); __builtin_amdgcn_s_setprio(0);
    SBAR;
    // ---- P2
    G_RD_B(0, 1, b1r);
    if constexpr (NF == 6) G_STG_B(1, 0, e + 1); else G_STG_B(1, 1, e + 1);
    SBAR; LGKM0;
    __builtin_amdgcn_s_setprio(1); G_MMA(0, 1, b1r); __builtin_amdgcn_s_setprio(0);
    SBAR;
    // ---- P3
    G_RD_A(0, 1);
    if constexpr (NF == 6) G_STG_B(1, 1, e + 1);
    SBAR; LGKM0;
    __builtin_amdgcn_s_setprio(1); G_MMA(1, 1, b1r); __builtin_amdgcn_s_setprio(0);
    SBAR;
    // ---- P4
    if (pf) G_STG_A(0, e + 2);
    SBAR; LGKM0;
    __builtin_amdgcn_s_setprio(1); G_MMA(1, 0, b0r); __builtin_amdgcn_s_setprio(0);
    if (pf) { VM2; } else { VM0; }
    SBAR;
    // ---- P5
    G_RD_A(1, 0);
    G_RD_B(1, 0, b0r);
    if (pf) G_STG_B(0, 0, e + 2);
    SBAR; LGKM0;
    __builtin_amdgcn_s_setprio(1); G_MMA(0, 0, b0r); __builtin_amdgcn_s_setprio(0);
    SBAR;
    // ---- P6
    G_RD_B(1, 1, b1r);
    if (pf) G_STG_B(0, 1, e + 2);
    SBAR; LGKM0;
    __builtin_amdgcn_s_setprio(1); G_MMA(0, 1, b1r); __builtin_amdgcn_s_setprio(0);
    SBAR;
    // ---- P7
    G_RD_A(1, 1);
    if constexpr (NF == 6) { if (pf) G_STG_B(0, 2, e + 2); }
    SBAR; LGKM0;
    __builtin_amdgcn_s_setprio(1); G_MMA(1, 1, b1r); __builtin_amdgcn_s_setprio(0);
    SBAR;
    // ---- P8
    if constexpr (NF == 6) { if (pf) G_STG_B(1, 2, e + 3); }
    else                   { if (pf) G_STG_A(1, e + 3); }
    SBAR; LGKM0;
    __builtin_amdgcn_s_setprio(1); G_MMA(1, 0, b0r); __builtin_amdgcn_s_setprio(0);
    VM2;
    SBAR;
  }

  // epilogue: C[row, col], col = frag col + la, row = lq*4 + r within frag
#pragma unroll
  for (int mf = 0; mf < 4; ++mf) {
    int row = m0 + wr * 64 + mf * 16 + lq * 4;
#pragma unroll
    for (int nf = 0; nf < NF; ++nf) {
      int col = n0 + wc * (NF * 16) + nf * 16 + la;
#pragma unroll
      for (int r = 0; r < 4; ++r)
        C[(size_t)(row + r) * N + col] = acc[mf][nf][r];
    }
  }
#undef G_STG_A
#undef G_STG_B
#undef G_RD_A
#undef G_RD_B
#undef G_MMA
}

// ---------------------------------------------------------------------------
// RoPE: read QKV fp32, write q_b (bf16 * CSC_, [B][NH][T][D]) and knew (fp32)
__global__ __launch_bounds__(256) void rope_kernel(const float* __restrict__ QKV,
                                                   const int* __restrict__ pos_ids,
                                                   unsigned short* __restrict__ q_b,
                                                   float* __restrict__ knew) {
  int idx = blockIdx.x * 256 + threadIdx.x;
  const int total = B_ * T_ * (NH_ + NKV_) * 32;
  if (idx >= total) return;
  int i = idx & 31;
  int tmp = idx >> 5;
  int hh = tmp % (NH_ + NKV_);
  int bt = tmp / (NH_ + NKV_);
  int t = bt & (T_ - 1);
  int b = bt >> 11;
  int pos = pos_ids[bt] + STEPS_;
  float inv = exp2f(-(float)i * (13.287712379549449f / 32.0f));
  float ang = (float)pos * inv;
  float sn, cs;
  sincosf(ang, &sn, &cs);
  const float* rowp = QKV + (size_t)bt * 3072;
  if (hh < NH_) {
    float x1 = rowp[hh * 64 + i];
    float x2 = rowp[hh * 64 + 32 + i];
    float y1 = (x1 * cs - x2 * sn) * CSC_;   // fold score scale into q
    float y2 = (x2 * cs + x1 * sn) * CSC_;
    size_t o = ((size_t)(b * NH_ + hh) * T_ + t) * HD_ + i;
    q_b[o] = f2bf(y1);
    q_b[o + 32] = f2bf(y2);
  } else {
    int kv = hh - NH_;
    float x1 = rowp[2048 + kv * 64 + i];
    float x2 = rowp[2048 + kv * 64 + 32 + i];
    float y1 = x1 * cs - x2 * sn;
    float y2 = x2 * cs + x1 * sn;
    size_t o = ((size_t)(b * NKV_ + kv) * T_ + t) * HD_ + i;
    knew[o] = y1;
    knew[o + 32] = y2;
  }
}

// ---------------------------------------------------------------------------
// Flash attention v2, swapped-QK^T, WITH FUSED EPILOGUE.
//
// Main loop unchanged from round 4 (verified). Tail now folds the two
// diagonal keys (prev_k[1], new k) directly: aq (bf16 q incl CSC, d-partition
// lq*8..+7 / 32+lq*8..+7) dots against k1/kn rows loaded in the SAME
// partition -> e1,e2 reduced over lq via shfl_xor(16|32); m_f/l_f already on
// the la row-domain. w0/w1/w2/denom per-row; 4 shfls move the 3 scalars to
// the O domain (row = lq*4+r); v1/vn loaded coalesced in O's (jd,la) layout;
// attnout written bf16 directly. Bit-identical math to the old standalone
// epilogue (o was stored/reloaded as raw fp32 before; all other reads same).
__global__ __launch_bounds__(256, 3) void flash_kernel(const unsigned short* __restrict__ qb,
                                                       const unsigned short* __restrict__ k0b,
                                                       const unsigned short* __restrict__ v0t,
                                                       const float* __restrict__ prev_k,
                                                       const float* __restrict__ prev_v,
                                                       const float* __restrict__ knew,
                                                       const float* __restrict__ QKV,
                                                       unsigned short* __restrict__ attnout) {
  __shared__ unsigned short sK[2][64 * 64];
  __shared__ unsigned short sV[2][64 * 64];
  __shared__ unsigned short sP[4][16 * 72];

  const int tid = threadIdx.x;
  const int lane = tid & 63;
  const int wave = tid >> 6;
  const int la = lane & 15;
  const int lq = lane >> 4;
  const int swz = la & 7;

  const int id = blockIdx.x;
  const int bh = (id & 7) * 8 + ((id >> 3) & 7);
  const int qt = 15 - (id >> 6);

  const size_t bhs = (size_t)bh;
  const unsigned short* gK = k0b + bhs * T_ * HD_;
  const unsigned short* gV = v0t + bhs * HD_ * T_;

  const int rb0 = qt * 128 + wave * 32;
  const int ktd = rb0 >> 6;
  const int ktmax = 2 * qt + 1;

  bf16x8 aq[2][2];
#pragma unroll
  for (int f = 0; f < 2; f++) {
    const unsigned short* qp = qb + (bhs * T_ + rb0 + f * 16 + la) * HD_;
    aq[f][0] = frag_ld(qp + lq * 8);
    aq[f][1] = frag_ld(qp + 32 + lq * 8);
  }

  f32x4 o[2][4] = {};
  float m_f[2] = {-1e30f, -1e30f};
  float l_f[2] = {0.0f, 0.0f};

  const int lrow = lane >> 3;
  const int lcb = (lane & 7) ^ lrow;

  {
    unsigned short* kd = &sK[0][wave * 1024];
    unsigned short* vd = &sV[0][wave * 1024];
    async_cp16(gK + (size_t)(wave * 16 + lrow) * HD_ + lcb * 8, kd);
    async_cp16(gK + (size_t)(wave * 16 + 8 + lrow) * HD_ + lcb * 8, kd + 512);
    async_cp16(gV + (size_t)(wave * 16 + lrow) * T_ + lcb * 8, vd);
    async_cp16(gV + (size_t)(wave * 16 + 8 + lrow) * T_ + lcb * 8, vd + 512);
  }
  __syncthreads();

  int cur = 0;
  for (int kt = 0; kt <= ktmax; ++kt) {
    if (kt < ktmax) {
      const int nk = (kt + 1) * 64;
      unsigned short* kd = &sK[cur ^ 1][wave * 1024];
      unsigned short* vd = &sV[cur ^ 1][wave * 1024];
      async_cp16(gK + (size_t)(nk + wave * 16 + lrow) * HD_ + lcb * 8, kd);
      async_cp16(gK + (size_t)(nk + wave * 16 + 8 + lrow) * HD_ + lcb * 8, kd + 512);
      async_cp16(gV + (size_t)(wave * 16 + lrow) * T_ + nk + lcb * 8, vd);
      async_cp16(gV + (size_t)(wave * 16 + 8 + lrow) * T_ + nk + lcb * 8, vd + 512);
    }

    if (kt <= ktd) {
      const unsigned short* kb = &sK[cur][0];
      const unsigned short* vb = &sV[cur][0];

      bf16x8 bk0[4], bk1[4];
#pragma unroll
      for (int nb = 0; nb < 4; nb++) {
        const unsigned short* rp = kb + (nb * 16 + la) * 64;
        bk0[nb] = frag_ld(rp + ((lq ^ swz) << 3));
        bk1[nb] = frag_ld(rp + (((lq + 4) ^ swz) << 3));
      }
      // S^T = K * Q^T : lane la = q-row (frag f), key = nb*16 + lq*4 + r
      f32x4 s[2][4];
      __builtin_amdgcn_s_setprio(1);
#pragma unroll
      for (int f = 0; f < 2; f++)
#pragma unroll
        for (int nb = 0; nb < 4; nb++) {
          f32x4 z = {0.f, 0.f, 0.f, 0.f};
          z = mfma16(bk0[nb], aq[f][0], z);
          z = mfma16(bk1[nb], aq[f][1], z);
          s[f][nb] = z;
        }
      __builtin_amdgcn_s_setprio(0);

      const bool diag = (kt == ktd);
#pragma unroll
      for (int f = 0; f < 2; f++) {
        const int qrow = rb0 + f * 16 + la;
        if (diag) {
#pragma unroll
          for (int nb = 0; nb < 4; nb++)
#pragma unroll
            for (int r = 0; r < 4; r++) {
              int key = kt * 64 + nb * 16 + lq * 4 + r;
              s[f][nb][r] = (key <= qrow) ? s[f][nb][r] : -1e30f;
            }
        }
        // in-register max over this lane's 16 keys, then across lq groups
        float t0 = fmaxf(fmaxf(s[f][0][0], s[f][0][1]), fmaxf(s[f][0][2], s[f][0][3]));
        float t1 = fmaxf(fmaxf(s[f][1][0], s[f][1][1]), fmaxf(s[f][1][2], s[f][1][3]));
        float t2 = fmaxf(fmaxf(s[f][2][0], s[f][2][1]), fmaxf(s[f][2][2], s[f][2][3]));
        float t3 = fmaxf(fmaxf(s[f][3][0], s[f][3][1]), fmaxf(s[f][3][2], s[f][3][3]));
        float tm = fmaxf(fmaxf(t0, t1), fmaxf(t2, t3));
        tm = fmaxf(tm, __shfl_xor(tm, 16));
        tm = fmaxf(tm, __shfl_xor(tm, 32));
        // defer-max (T13): only rescale when some row's max grew past m+8
        const bool resc = __any(tm > m_f[f] + 8.0f);
        if (resc) {
          float mn = fmaxf(m_f[f], tm);
          float al = exp2f(m_f[f] - mn);
          m_f[f] = mn;
          l_f[f] *= al;
          // al lives on lane (la = qrow); O accumulator has qrow = lq*4+r
          float a0 = __shfl(al, lq * 4 + 0);
          float a1 = __shfl(al, lq * 4 + 1);
          float a2 = __shfl(al, lq * 4 + 2);
          float a3 = __shfl(al, lq * 4 + 3);
#pragma unroll
          for (int jd = 0; jd < 4; jd++) {
            o[f][jd][0] *= a0;
            o[f][jd][1] *= a1;
            o[f][jd][2] *= a2;
            o[f][jd][3] *= a3;
          }
        }
        float ls = 0.0f;
#pragma unroll
        for (int nb = 0; nb < 4; nb++)
#pragma unroll
          for (int r = 0; r < 4; r++) {
            float p = exp2f(s[f][nb][r] - m_f[f]);
            s[f][nb][r] = p;
            ls += p;
          }
        ls += __shfl_xor(ls, 16);
        ls += __shfl_xor(ls, 32);
        l_f[f] += ls;
      }

      bf16x8 bv0[4], bv1[4];
#pragma unroll
      for (int jd = 0; jd < 4; jd++) {
        const unsigned short* rp = vb + (jd * 16 + la) * 64;
        bv0[jd] = frag_ld(rp + ((lq ^ swz) << 3));
        bv1[jd] = frag_ld(rp + (((lq + 4) ^ swz) << 3));
      }
      unsigned short* pw = &sP[wave][0];
#pragma unroll
      for (int f = 0; f < 2; f++) {
#pragma unroll
        for (int nb = 0; nb < 4; nb++) {
          unsigned int p01 = cvtpk_bf16(s[f][nb][0], s[f][nb][1]);
          unsigned int p23 = cvtpk_bf16(s[f][nb][2], s[f][nb][3]);
          unsigned long long pq = ((unsigned long long)p23 << 32) | (unsigned long long)p01;
          *(unsigned long long*)(pw + la * 72 + nb * 16 + lq * 4) = pq;
        }
        bf16x8 ap0 = frag_ld(&pw[la * 72 + lq * 8]);
        bf16x8 ap1 = frag_ld(&pw[la * 72 + 32 + lq * 8]);
        __builtin_amdgcn_s_setprio(1);
#pragma unroll
        for (int jd = 0; jd < 4; jd++) {
          o[f][jd] = mfma16(ap0, bv0[jd], o[f][jd]);
          o[f][jd] = mfma16(ap1, bv1[jd], o[f][jd]);
        }
        __builtin_amdgcn_s_setprio(0);
      }
    }
    __syncthreads();
    cur ^= 1;
  }

  // ---- fused epilogue: fold diagonal keys (prev_k[1], new k) and write bf16
  const int bI = bh >> 5;
  const int hI = bh & 31;
  const int kvI = hI >> 2;
  const size_t P1 = (size_t)B_ * NH_ * T_ * HD_;
  const float* k1base = prev_k + P1 + bhs * T_ * HD_;
  const float* v1base = prev_v + P1 + bhs * T_ * HD_;
  const float* knbase = knew + ((size_t)bI * NKV_ + kvI) * T_ * HD_;
  const float* vnbase = QKV + (size_t)bI * T_ * 3072 + 2560 + kvI * 64;
  unsigned short* aobase = attnout + (size_t)bI * T_ * (NH_ * HD_) + hI * HD_;

#pragma unroll
  for (int f = 0; f < 2; f++) {
    const int rowA = rb0 + f * 16 + la;   // dot-domain row (la), all lq share
    const float* k1p = k1base + (size_t)rowA * HD_;
    const float* knp = knbase + (size_t)rowA * HD_;
    float e1 = 0.f, e2 = 0.f;
#pragma unroll
    for (int h2 = 0; h2 < 2; h2++) {
      const int dd = h2 * 32 + lq * 8;
#pragma unroll
      for (int j = 0; j < 8; j++) {
        float qv = (float)aq[f][h2][j];   // bf16 q incl CSC_ (== old q_b read)
        e1 = fmaf(qv, k1p[dd + j], e1);
        e2 = fmaf(qv, knp[dd + j], e2);
      }
    }
    e1 += __shfl_xor(e1, 16); e1 += __shfl_xor(e1, 32);
    e2 += __shfl_xor(e2, 16); e2 += __shfl_xor(e2, 32);
    float mx = fmaxf(m_f[f], fmaxf(e1, e2));
    float w0 = exp2f(m_f[f] - mx);
    float w1 = exp2f(e1 - mx);
    float w2 = exp2f(e2 - mx);
    float inv = 1.0f / (l_f[f] * w0 + w1 + w2);
    float s0 = w0 * inv, s1 = w1 * inv, s2 = w2 * inv;
    // move per-row scalars (on lanes 0..15) to the O domain (row = lq*4+r)
    float a0[4], a1[4], a2[4];
#pragma unroll
    for (int r = 0; r < 4; r++) {
      a0[r] = __shfl(s0, lq * 4 + r);
      a1[r] = __shfl(s1, lq * 4 + r);
      a2[r] = __shfl(s2, lq * 4 + r);
    }
#pragma unroll
    for (int r = 0; r < 4; r++) {
      const int rowO = rb0 + f * 16 + lq * 4 + r;
      const float* v1p = v1base + (size_t)rowO * HD_;
      const float* vnp = vnbase + (size_t)rowO * 3072;
      unsigned short* aop = aobase + (size_t)rowO * (NH_ * HD_);
#pragma unroll
      for (int jd = 0; jd < 4; jd++) {
        int d = jd * 16 + la;
        float out = o[f][jd][r] * a0[r] + v1p[d] * a1[r] + vnp[d] * a2[r];
        aop[d] = f2bf(out);
      }
    }
  }
}

// ---------------------------------------------------------------------------
// Workspace layout (bytes; needs ws_size >= 178,257,920)
#define OFF_QKV   ((size_t)0)
#define OFF_XB    ((size_t)50331648)
#define OFF_WQKVT ((size_t)83886080)
#define OFF_WOT   ((size_t)109051904)
#define OFF_QB    ((size_t)117440512)
#define OFF_K0B   ((size_t)134217728)
#define OFF_V0T   ((size_t)150994944)
#define OFF_KNEW  ((size_t)167772160)
#define OFF_ML    ((size_t)176160768)

extern "C" void kernel_launch(void* const* d_in, const int* in_sizes, int n_in,
                              void* d_out, int out_size, void* d_ws, size_t ws_size,
                              hipStream_t stream) {
  const float* X = (const float*)d_in[0];
  const int* pos = (const int*)d_in[2];
  const float* prevk = (const float*)d_in[3];
  const float* prevv = (const float*)d_in[4];
  const float* Wq = (const float*)d_in[5];
  const float* Wk = (const float*)d_in[6];
  const float* Wv = (const float*)d_in[7];
  const float* Wo = (const float*)d_in[8];

  char* ws = (char*)d_ws;
  float* QKV = (float*)(ws + OFF_QKV);
  unsigned short* Xb = (unsigned short*)(ws + OFF_XB);
  unsigned short* WqkvT = (unsigned short*)(ws + OFF_WQKVT);
  unsigned short* attnout = (unsigned short*)(ws + OFF_WQKVT);
  unsigned short* WoT = (unsigned short*)(ws + OFF_WOT);
  unsigned short* q_b = (unsigned short*)(ws + OFF_QB);
  unsigned short* k0b = (unsigned short*)(ws + OFF_K0B);
  unsigned short* v0t = (unsigned short*)(ws + OFF_V0T);
  float* knew = (float*)(ws + OFF_KNEW);

  convert_bf16<<<16384, 256, 0, stream>>>(X, Xb, 4194304);
  transpose_f32_bf16_ld<<<dim3(32, 64), 256, 0, stream>>>(Wq, WqkvT, 4096, 2048, 4096);
  transpose_f32_bf16_ld<<<dim3(8, 64), 256, 0, stream>>>(Wk, WqkvT + (size_t)2048 * 4096, 4096, 512, 4096);
  transpose_f32_bf16_ld<<<dim3(8, 64), 256, 0, stream>>>(Wv, WqkvT + (size_t)2560 * 4096, 4096, 512, 4096);
  transpose_f32_bf16_ld<<<dim3(32, 32), 256, 0, stream>>>(Wo, WoT, 2048, 2048, 2048);
  convert_bf16<<<8192, 256, 0, stream>>>(prevk, k0b, 2097152);
  transpose_v0<<<dim3(32, 64), 256, 0, stream>>>(prevv, v0t);

  // QKV GEMM: M=4096, N=3072, K=4096; BM=128, BN=384 -> grid 32x8 = 256
  gemm128_bt<6><<<dim3(32, 8), 512, 0, stream>>>(Xb, WqkvT, QKV, 4096, 3072, 4096);

  rope_kernel<<<20480, 256, 0, stream>>>(QKV, pos, q_b, knew);

  // flash with fused diagonal-key epilogue -> writes attnout bf16 directly
  flash_kernel<<<1024, 256, 0, stream>>>(q_b, k0b, v0t, prevk, prevv, knew, QKV, attnout);

  // Wo GEMM: M=4096, N=2048, K=2048; BM=128, BN=256 -> grid 32x8 = 256
  gemm128_bt<4><<<dim3(32, 8), 512, 0, stream>>>(attnout, WoT, (float*)d_out, 4096, 2048, 2048);
}

// Round 6
// 503.050 us; speedup vs baseline: 1.2577x; 1.0297x over previous
//
#include <hip/hip_runtime.h>

// Problem constants
#define B_    2
#define T_    2048
#define HID_  2048
#define NH_   32
#define NKV_  8
#define HD_   64
#define STEPS_ 2
#define SCALE_ 0.125f
// SCALE * log2(e): scores kept in exp2 domain throughout (folded into q at RoPE)
#define CSC_  0.18033688011112042f

typedef float   f32x4  __attribute__((ext_vector_type(4)));
typedef __bf16  bf16x8 __attribute__((ext_vector_type(8)));
typedef unsigned short u16x8 __attribute__((ext_vector_type(8)));

__device__ __forceinline__ unsigned short f2bf(float f) {
  unsigned int u = __builtin_bit_cast(unsigned int, f);
  u = (u + 0x7fffu + ((u >> 16) & 1u)) >> 16;
  return (unsigned short)u;
}
__device__ __forceinline__ float bf2f(unsigned short h) {
  unsigned int u = ((unsigned int)h) << 16;
  return __builtin_bit_cast(float, u);
}
__device__ __forceinline__ bf16x8 frag_ld(const unsigned short* p) {
  u16x8 v = *(const u16x8*)p;
  return __builtin_bit_cast(bf16x8, v);
}
__device__ __forceinline__ f32x4 mfma16(bf16x8 a, bf16x8 b, f32x4 c) {
  return __builtin_amdgcn_mfma_f32_16x16x32_bf16(a, b, c, 0, 0, 0);
}
__device__ __forceinline__ void async_cp16(const void* g, void* l) {
  __builtin_amdgcn_global_load_lds(
      (const __attribute__((address_space(1))) void*)g,
      (__attribute__((address_space(3))) void*)l, 16, 0, 0);
}
// HW packed f32->bf16 (RNE), no builtin on gfx950 -> inline asm (guide T12)
__device__ __forceinline__ unsigned int cvtpk_bf16(float lo, float hi) {
  unsigned int r;
  asm("v_cvt_pk_bf16_f32 %0, %1, %2" : "=v"(r) : "v"(lo), "v"(hi));
  return r;
}

// ---------------------------------------------------------------------------
// elementwise fp32 -> bf16 convert (float4 per thread)
__global__ __launch_bounds__(256) void convert_bf16(const float* __restrict__ in,
                                                    unsigned short* __restrict__ out,
                                                    int n4) {
  int idx = blockIdx.x * 256 + threadIdx.x;
  if (idx < n4) {
    float4 v = ((const float4*)in)[idx];
    ushort4 o;
    o.x = f2bf(v.x); o.y = f2bf(v.y); o.z = f2bf(v.z); o.w = f2bf(v.w);
    ((ushort4*)out)[idx] = o;
  }
}

// transpose + convert: in (K x N fp32 row-major) -> out (N x K bf16, ld=ldo)
__global__ __launch_bounds__(256) void transpose_f32_bf16_ld(const float* __restrict__ in,
                                                             unsigned short* __restrict__ out,
                                                             int K, int N, int ldo) {
  __shared__ float tile[64][65];
  int n0 = blockIdx.x * 64, k0 = blockIdx.y * 64;
  int c = threadIdx.x & 63, w = threadIdx.x >> 6;
#pragma unroll
  for (int i = 0; i < 16; i++) {
    int r = w * 16 + i;
    tile[r][c] = in[(size_t)(k0 + r) * N + n0 + c];
  }
  __syncthreads();
#pragma unroll
  for (int i = 0; i < 16; i++) {
    int rr = w * 16 + i;
    out[(size_t)(n0 + rr) * ldo + k0 + c] = f2bf(tile[c][rr]);
  }
}

// v0 (B*NH slabs of [T][D] fp32) -> v0t bf16 [B*NH][D][T]
__global__ __launch_bounds__(256) void transpose_v0(const float* __restrict__ v0,
                                                    unsigned short* __restrict__ v0t) {
  __shared__ float tile[64][65];
  int s0 = blockIdx.x * 64;
  int bh = blockIdx.y;
  const float* src = v0 + (size_t)bh * T_ * HD_;
  unsigned short* dst = v0t + (size_t)bh * HD_ * T_;
  int c = threadIdx.x & 63, w = threadIdx.x >> 6;
#pragma unroll
  for (int i = 0; i < 16; i++) {
    int r = w * 16 + i;
    tile[r][c] = src[(size_t)(s0 + r) * HD_ + c];
  }
  __syncthreads();
#pragma unroll
  for (int i = 0; i < 16; i++) {
    int rr = w * 16 + i;
    dst[(size_t)rr * T_ + s0 + c] = f2bf(tile[c][rr]);
  }
}

// ---------------------------------------------------------------------------
// 128 x (NF*64) 8-phase bf16 GEMM: C(MxN fp32) = A(MxK) * Bt(NxK)^T
// (unchanged from round 4 -- verified; see that round's ledger comments)
// ---------------------------------------------------------------------------
#define SBAR  do { __builtin_amdgcn_sched_barrier(0); __builtin_amdgcn_s_barrier(); \
                   __builtin_amdgcn_sched_barrier(0); } while (0)
#define LGKM0 do { asm volatile("s_waitcnt lgkmcnt(0)" ::: "memory"); \
                   __builtin_amdgcn_sched_barrier(0); } while (0)
#define VM2   do { asm volatile("s_waitcnt vmcnt(2)" ::: "memory"); } while (0)
#define VM0   do { asm volatile("s_waitcnt vmcnt(0)" ::: "memory"); } while (0)

template <int NF>
__global__ __launch_bounds__(512, 2) void gemm128_bt(const unsigned short* __restrict__ A,
                                                     const unsigned short* __restrict__ Bt,
                                                     float* __restrict__ C,
                                                     int M, int N, int K) {
  constexpr int NHF = NF / 2;             // B frags per qn group per wave
  constexpr int BROWS = 128 + NF * 64;    // rows staged per buffer
  __shared__ __attribute__((aligned(128))) unsigned short smem[2][BROWS * 64];

  const int tid  = threadIdx.x;
  const int lane = tid & 63;
  const int wid  = tid >> 6;      // 0..7
  const int wr   = wid >> 2;      // 0..1  (M half: 64 rows)
  const int wc   = wid & 3;       // 0..3  (N quarter: NF*16 cols)
  const int la   = lane & 15;
  const int lq   = lane >> 4;
  const int sw   = la & 7;        // read-side swizzle key (row&7 == la&7)
  const int m0   = blockIdx.x * 128;
  const int n0   = blockIdx.y * (NF * 64);

  // staging: chunk = wid*2+is (1 KiB, 8 rows); lane covers physical
  // (row = chunk*8 + (lane>>3), slot = lane&7); fetches logical slot
  // (lane&7)^(row&7) so the linear DMA image realizes the XOR swizzle.
  const int sr = lane >> 3;
  const int sl = (lane & 7) ^ sr;

  const unsigned short* gA[2];
  const unsigned short* gB[NHF][2];
#pragma unroll
  for (int is = 0; is < 2; ++is) {
    int r = (wid * 2 + is) * 8 + sr;
    gA[is] = A + (size_t)(m0 + r) * K + sl * 8;
#pragma unroll
    for (int u = 0; u < NHF; ++u)
      gB[u][is] = Bt + (size_t)(n0 + u * 128 + r) * K + sl * 8;
  }

#define G_STG_A(buf, kt) do { \
    async_cp16(gA[0] + (size_t)(kt) * 64, &smem[buf][(wid * 2 + 0) * 512]); \
    async_cp16(gA[1] + (size_t)(kt) * 64, &smem[buf][(wid * 2 + 1) * 512]); \
  } while (0)
#define G_STG_B(buf, u, kt) do { \
    async_cp16(gB[u][0] + (size_t)(kt) * 64, &smem[buf][(128 + (u) * 128) * 64 + (wid * 2 + 0) * 512]); \
    async_cp16(gB[u][1] + (size_t)(kt) * 64, &smem[buf][(128 + (u) * 128) * 64 + (wid * 2 + 1) * 512]); \
  } while (0)

  f32x4  acc[4][NF] = {};
  bf16x8 aR[2][2], b0r[NHF][2], b1r[NHF][2];

#define G_RD_A(buf, qm) do { \
    const unsigned short* rp_ = &smem[buf][0]; \
    _Pragma("unroll") \
    for (int i_ = 0; i_ < 2; ++i_) { \
      int ro_ = (wr * 64 + (qm) * 32 + i_ * 16 + la) * 64; \
      aR[i_][0] = frag_ld(rp_ + ro_ + (((0 + lq) ^ sw) << 3)); \
      aR[i_][1] = frag_ld(rp_ + ro_ + (((4 + lq) ^ sw) << 3)); \
    } \
  } while (0)
#define G_RD_B(buf, qn, breg) do { \
    const unsigned short* rp_ = &smem[buf][128 * 64]; \
    _Pragma("unroll") \
    for (int j_ = 0; j_ < NHF; ++j_) { \
      int ro_ = (wc * (NF * 16) + (qn) * (NF * 8) + j_ * 16 + la) * 64; \
      breg[j_][0] = frag_ld(rp_ + ro_ + (((0 + lq) ^ sw) << 3)); \
      breg[j_][1] = frag_ld(rp_ + ro_ + (((4 + lq) ^ sw) << 3)); \
    } \
  } while (0)
#define G_MMA(qm, qn, breg) do { \
    _Pragma("unroll") \
    for (int i_ = 0; i_ < 2; ++i_) \
      _Pragma("unroll") \
      for (int j_ = 0; j_ < NHF; ++j_) { \
        f32x4 c_ = acc[(qm) * 2 + i_][(qn) * NHF + j_]; \
        c_ = mfma16(aR[i_][0], breg[j_][0], c_); \
        c_ = mfma16(aR[i_][1], breg[j_][1], c_); \
        acc[(qm) * 2 + i_][(qn) * NHF + j_] = c_; \
      } \
  } while (0)

  // prologue: tile0 fully -> buf0; tile1's prev-P8-role slot -> buf1.
  G_STG_A(0, 0);
#pragma unroll
  for (int u = 0; u < NHF; ++u) G_STG_B(0, u, 0);
  if constexpr (NF == 6) G_STG_B(1, 2, 1); else G_STG_A(1, 1);
  VM2;   // tile0's slots landed; the buf1 slot may stay in flight
  SBAR;

  const int NI = K >> 7;   // iterations of 2 K-tiles (K multiple of 128)
  for (int it = 0; it < NI; ++it) {
    const int e = it * 2;
    const bool pf = (it + 1 < NI);
    // ---- P1
    G_RD_A(0, 0);
    G_RD_B(0, 0, b0r);
    if constexpr (NF == 6) G_STG_A(1, e + 1); else G_STG_B(1, 0, e + 1);
    SBAR; LGKM0;
    __builtin_amdgcn_s_setprio(1); G_MMA(0, 0, b0r); __builtin_amdgcn_s_setprio(0);
    SBAR;
    // ---- P2
    G_RD_B(0, 1, b1r);
    if constexpr (NF == 6) G_STG_B(1, 0, e + 1); else G_STG_B(1, 1, e + 1);
    SBAR; LGKM0;
    __builtin_amdgcn_s_setprio(1); G_MMA(0, 1, b1r); __builtin_amdgcn_s_setprio(0);
    SBAR;
    // ---- P3
    G_RD_A(0, 1);
    if constexpr (NF == 6) G_STG_B(1, 1, e + 1);
    SBAR; LGKM0;
    __builtin_amdgcn_s_setprio(1); G_MMA(1, 1, b1r); __builtin_amdgcn_s_setprio(0);
    SBAR;
    // ---- P4
    if (pf) G_STG_A(0, e + 2);
    SBAR; LGKM0;
    __builtin_amdgcn_s_setprio(1); G_MMA(1, 0, b0r); __builtin_amdgcn_s_setprio(0);
    if (pf) { VM2; } else { VM0; }
    SBAR;
    // ---- P5
    G_RD_A(1, 0);
    G_RD_B(1, 0, b0r);
    if (pf) G_STG_B(0, 0, e + 2);
    SBAR; LGKM0;
    __builtin_amdgcn_s_setprio(1); G_MMA(0, 0, b0r); __builtin_amdgcn_s_setprio(0);
    SBAR;
    // ---- P6
    G_RD_B(1, 1, b1r);
    if (pf) G_STG_B(0, 1, e + 2);
    SBAR; LGKM0;
    __builtin_amdgcn_s_setprio(1); G_MMA(0, 1, b1r); __builtin_amdgcn_s_setprio(0);
    SBAR;
    // ---- P7
    G_RD_A(1, 1);
    if constexpr (NF == 6) { if (pf) G_STG_B(0, 2, e + 2); }
    SBAR; LGKM0;
    __builtin_amdgcn_s_setprio(1); G_MMA(1, 1, b1r); __builtin_amdgcn_s_setprio(0);
    SBAR;
    // ---- P8
    if constexpr (NF == 6) { if (pf) G_STG_B(1, 2, e + 3); }
    else                   { if (pf) G_STG_A(1, e + 3); }
    SBAR; LGKM0;
    __builtin_amdgcn_s_setprio(1); G_MMA(1, 0, b0r); __builtin_amdgcn_s_setprio(0);
    VM2;
    SBAR;
  }

  // epilogue: C[row, col], col = frag col + la, row = lq*4 + r within frag
#pragma unroll
  for (int mf = 0; mf < 4; ++mf) {
    int row = m0 + wr * 64 + mf * 16 + lq * 4;
#pragma unroll
    for (int nf = 0; nf < NF; ++nf) {
      int col = n0 + wc * (NF * 16) + nf * 16 + la;
#pragma unroll
      for (int r = 0; r < 4; ++r)
        C[(size_t)(row + r) * N + col] = acc[mf][nf][r];
    }
  }
#undef G_STG_A
#undef G_STG_B
#undef G_RD_A
#undef G_RD_B
#undef G_MMA
}

// ---------------------------------------------------------------------------
// RoPE: read QKV fp32, write q_b (bf16 * CSC_, [B][NH][T][D]) and knew (fp32)
__global__ __launch_bounds__(256) void rope_kernel(const float* __restrict__ QKV,
                                                   const int* __restrict__ pos_ids,
                                                   unsigned short* __restrict__ q_b,
                                                   float* __restrict__ knew) {
  int idx = blockIdx.x * 256 + threadIdx.x;
  const int total = B_ * T_ * (NH_ + NKV_) * 32;
  if (idx >= total) return;
  int i = idx & 31;
  int tmp = idx >> 5;
  int hh = tmp % (NH_ + NKV_);
  int bt = tmp / (NH_ + NKV_);
  int t = bt & (T_ - 1);
  int b = bt >> 11;
  int pos = pos_ids[bt] + STEPS_;
  float inv = exp2f(-(float)i * (13.287712379549449f / 32.0f));
  float ang = (float)pos * inv;
  float sn, cs;
  sincosf(ang, &sn, &cs);
  const float* rowp = QKV + (size_t)bt * 3072;
  if (hh < NH_) {
    float x1 = rowp[hh * 64 + i];
    float x2 = rowp[hh * 64 + 32 + i];
    float y1 = (x1 * cs - x2 * sn) * CSC_;   // fold score scale into q
    float y2 = (x2 * cs + x1 * sn) * CSC_;
    size_t o = ((size_t)(b * NH_ + hh) * T_ + t) * HD_ + i;
    q_b[o] = f2bf(y1);
    q_b[o + 32] = f2bf(y2);
  } else {
    int kv = hh - NH_;
    float x1 = rowp[2048 + kv * 64 + i];
    float x2 = rowp[2048 + kv * 64 + 32 + i];
    float y1 = x1 * cs - x2 * sn;
    float y2 = x2 * cs + x1 * sn;
    size_t o = ((size_t)(b * NKV_ + kv) * T_ + t) * HD_ + i;
    knew[o] = y1;
    knew[o + 32] = y2;
  }
}

// ---------------------------------------------------------------------------
// Flash attention v2, swapped-QK^T, fused epilogue, LOW-LATENCY SOFTMAX.
//
// Changes vs round 5 (main loop staging/barriers untouched):
//  - l is a PER-LANE PARTIAL (this lane's 16-key slice); the lq-axis
//    reduction (2 shfl) runs ONCE in the tail instead of per tile. On
//    rescale, l_part *= al is correct because al is row-uniform.
//  - defer-max check is per-lane: __any(tm_lane > m+8). The cross-lane max
//    (2 shfl) runs only in the rare rescale branch -> common-path softmax
//    has ZERO cross-lane/DS ops (15 max + 16 exp2 + 16 fma per f).
//  - sP split per f ([4][2][16*72], +9KB -> 51200B, still 3 blocks/CU):
//    write P for BOTH f, then read+MMA both -> one LDS write->read
//    latency wait per tile instead of two serial ones.
//  - V fragment reads issued before softmax so their DS latency hides
//    under the exp2/VALU work.
__global__ __launch_bounds__(256, 3) void flash_kernel(const unsigned short* __restrict__ qb,
                                                       const unsigned short* __restrict__ k0b,
                                                       const unsigned short* __restrict__ v0t,
                                                       const float* __restrict__ prev_k,
                                                       const float* __restrict__ prev_v,
                                                       const float* __restrict__ knew,
                                                       const float* __restrict__ QKV,
                                                       unsigned short* __restrict__ attnout) {
  __shared__ unsigned short sK[2][64 * 64];
  __shared__ unsigned short sV[2][64 * 64];
  __shared__ unsigned short sP[4][2][16 * 72];

  const int tid = threadIdx.x;
  const int lane = tid & 63;
  const int wave = tid >> 6;
  const int la = lane & 15;
  const int lq = lane >> 4;
  const int swz = la & 7;

  const int id = blockIdx.x;
  const int bh = (id & 7) * 8 + ((id >> 3) & 7);
  const int qt = 15 - (id >> 6);

  const size_t bhs = (size_t)bh;
  const unsigned short* gK = k0b + bhs * T_ * HD_;
  const unsigned short* gV = v0t + bhs * HD_ * T_;

  const int rb0 = qt * 128 + wave * 32;
  const int ktd = rb0 >> 6;
  const int ktmax = 2 * qt + 1;

  bf16x8 aq[2][2];
#pragma unroll
  for (int f = 0; f < 2; f++) {
    const unsigned short* qp = qb + (bhs * T_ + rb0 + f * 16 + la) * HD_;
    aq[f][0] = frag_ld(qp + lq * 8);
    aq[f][1] = frag_ld(qp + 32 + lq * 8);
  }

  f32x4 o[2][4] = {};
  float m_f[2] = {-1e30f, -1e30f};
  float l_p[2] = {0.0f, 0.0f};   // per-lane partial row-sum (lq-slice)

  const int lrow = lane >> 3;
  const int lcb = (lane & 7) ^ lrow;

  {
    unsigned short* kd = &sK[0][wave * 1024];
    unsigned short* vd = &sV[0][wave * 1024];
    async_cp16(gK + (size_t)(wave * 16 + lrow) * HD_ + lcb * 8, kd);
    async_cp16(gK + (size_t)(wave * 16 + 8 + lrow) * HD_ + lcb * 8, kd + 512);
    async_cp16(gV + (size_t)(wave * 16 + lrow) * T_ + lcb * 8, vd);
    async_cp16(gV + (size_t)(wave * 16 + 8 + lrow) * T_ + lcb * 8, vd + 512);
  }
  __syncthreads();

  int cur = 0;
  for (int kt = 0; kt <= ktmax; ++kt) {
    if (kt < ktmax) {
      const int nk = (kt + 1) * 64;
      unsigned short* kd = &sK[cur ^ 1][wave * 1024];
      unsigned short* vd = &sV[cur ^ 1][wave * 1024];
      async_cp16(gK + (size_t)(nk + wave * 16 + lrow) * HD_ + lcb * 8, kd);
      async_cp16(gK + (size_t)(nk + wave * 16 + 8 + lrow) * HD_ + lcb * 8, kd + 512);
      async_cp16(gV + (size_t)(wave * 16 + lrow) * T_ + nk + lcb * 8, vd);
      async_cp16(gV + (size_t)(wave * 16 + 8 + lrow) * T_ + nk + lcb * 8, vd + 512);
    }

    if (kt <= ktd) {
      const unsigned short* kb = &sK[cur][0];
      const unsigned short* vb = &sV[cur][0];

      bf16x8 bk0[4], bk1[4];
#pragma unroll
      for (int nb = 0; nb < 4; nb++) {
        const unsigned short* rp = kb + (nb * 16 + la) * 64;
        bk0[nb] = frag_ld(rp + ((lq ^ swz) << 3));
        bk1[nb] = frag_ld(rp + (((lq + 4) ^ swz) << 3));
      }
      // S^T = K * Q^T : lane la = q-row (frag f), key = nb*16 + lq*4 + r
      f32x4 s[2][4];
      __builtin_amdgcn_s_setprio(1);
#pragma unroll
      for (int f = 0; f < 2; f++)
#pragma unroll
        for (int nb = 0; nb < 4; nb++) {
          f32x4 z = {0.f, 0.f, 0.f, 0.f};
          z = mfma16(bk0[nb], aq[f][0], z);
          z = mfma16(bk1[nb], aq[f][1], z);
          s[f][nb] = z;
        }
      __builtin_amdgcn_s_setprio(0);

      // V fragment reads issued early: DS latency hides under softmax VALU
      bf16x8 bv0[4], bv1[4];
#pragma unroll
      for (int jd = 0; jd < 4; jd++) {
        const unsigned short* rp = vb + (jd * 16 + la) * 64;
        bv0[jd] = frag_ld(rp + ((lq ^ swz) << 3));
        bv1[jd] = frag_ld(rp + (((lq + 4) ^ swz) << 3));
      }

      const bool diag = (kt == ktd);
#pragma unroll
      for (int f = 0; f < 2; f++) {
        const int qrow = rb0 + f * 16 + la;
        if (diag) {
#pragma unroll
          for (int nb = 0; nb < 4; nb++)
#pragma unroll
            for (int r = 0; r < 4; r++) {
              int key = kt * 64 + nb * 16 + lq * 4 + r;
              s[f][nb][r] = (key <= qrow) ? s[f][nb][r] : -1e30f;
            }
        }
        // per-lane max over this lane's 16 keys (no cross-lane in common path)
        float t0 = fmaxf(fmaxf(s[f][0][0], s[f][0][1]), fmaxf(s[f][0][2], s[f][0][3]));
        float t1 = fmaxf(fmaxf(s[f][1][0], s[f][1][1]), fmaxf(s[f][1][2], s[f][1][3]));
        float t2 = fmaxf(fmaxf(s[f][2][0], s[f][2][1]), fmaxf(s[f][2][2], s[f][2][3]));
        float t3 = fmaxf(fmaxf(s[f][3][0], s[f][3][1]), fmaxf(s[f][3][2], s[f][3][3]));
        float tm = fmaxf(fmaxf(t0, t1), fmaxf(t2, t3));
        // defer-max (T13): rescale only if some lane's slice-max passed m+8
        const bool resc = __any(tm > m_f[f] + 8.0f);
        if (resc) {
          tm = fmaxf(tm, __shfl_xor(tm, 16));
          tm = fmaxf(tm, __shfl_xor(tm, 32));
          float mn = fmaxf(m_f[f], tm);
          float al = exp2f(m_f[f] - mn);   // row-uniform across lq
          m_f[f] = mn;
          l_p[f] *= al;
          // al lives on lane (la = qrow); O accumulator has qrow = lq*4+r
          float a0 = __shfl(al, lq * 4 + 0);
          float a1 = __shfl(al, lq * 4 + 1);
          float a2 = __shfl(al, lq * 4 + 2);
          float a3 = __shfl(al, lq * 4 + 3);
#pragma unroll
          for (int jd = 0; jd < 4; jd++) {
            o[f][jd][0] *= a0;
            o[f][jd][1] *= a1;
            o[f][jd][2] *= a2;
            o[f][jd][3] *= a3;
          }
        }
        float ls = 0.0f;
#pragma unroll
        for (int nb = 0; nb < 4; nb++)
#pragma unroll
          for (int r = 0; r < 4; r++) {
            float p = exp2f(s[f][nb][r] - m_f[f]);
            s[f][nb][r] = p;
            ls += p;
          }
        l_p[f] += ls;   // per-lane partial; lq-reduction deferred to tail
        // write this f's P into its own sP half (both halves live at once)
        unsigned short* pw = &sP[wave][f][0];
#pragma unroll
        for (int nb = 0; nb < 4; nb++) {
          unsigned int p01 = cvtpk_bf16(s[f][nb][0], s[f][nb][1]);
          unsigned int p23 = cvtpk_bf16(s[f][nb][2], s[f][nb][3]);
          unsigned long long pq = ((unsigned long long)p23 << 32) | (unsigned long long)p01;
          *(unsigned long long*)(pw + la * 72 + nb * 16 + lq * 4) = pq;
        }
      }

      // PV: one LDS round-trip wait covers both f halves
#pragma unroll
      for (int f = 0; f < 2; f++) {
        const unsigned short* pr = &sP[wave][f][0];
        bf16x8 ap0 = frag_ld(&pr[la * 72 + lq * 8]);
        bf16x8 ap1 = frag_ld(&pr[la * 72 + 32 + lq * 8]);
        __builtin_amdgcn_s_setprio(1);
#pragma unroll
        for (int jd = 0; jd < 4; jd++) {
          o[f][jd] = mfma16(ap0, bv0[jd], o[f][jd]);
          o[f][jd] = mfma16(ap1, bv1[jd], o[f][jd]);
        }
        __builtin_amdgcn_s_setprio(0);
      }
    }
    __syncthreads();
    cur ^= 1;
  }

  // finalize l: reduce the per-lane partials over the lq axis (once)
#pragma unroll
  for (int f = 0; f < 2; f++) {
    l_p[f] += __shfl_xor(l_p[f], 16);
    l_p[f] += __shfl_xor(l_p[f], 32);
  }

  // ---- fused epilogue: fold diagonal keys (prev_k[1], new k) and write bf16
  const int bI = bh >> 5;
  const int hI = bh & 31;
  const int kvI = hI >> 2;
  const size_t P1 = (size_t)B_ * NH_ * T_ * HD_;
  const float* k1base = prev_k + P1 + bhs * T_ * HD_;
  const float* v1base = prev_v + P1 + bhs * T_ * HD_;
  const float* knbase = knew + ((size_t)bI * NKV_ + kvI) * T_ * HD_;
  const float* vnbase = QKV + (size_t)bI * T_ * 3072 + 2560 + kvI * 64;
  unsigned short* aobase = attnout + (size_t)bI * T_ * (NH_ * HD_) + hI * HD_;

#pragma unroll
  for (int f = 0; f < 2; f++) {
    const int rowA = rb0 + f * 16 + la;   // dot-domain row (la), all lq share
    const float* k1p = k1base + (size_t)rowA * HD_;
    const float* knp = knbase + (size_t)rowA * HD_;
    float e1 = 0.f, e2 = 0.f;
#pragma unroll
    for (int h2 = 0; h2 < 2; h2++) {
      const int dd = h2 * 32 + lq * 8;
#pragma unroll
      for (int j = 0; j < 8; j++) {
        float qv = (float)aq[f][h2][j];   // bf16 q incl CSC_ (== old q_b read)
        e1 = fmaf(qv, k1p[dd + j], e1);
        e2 = fmaf(qv, knp[dd + j], e2);
      }
    }
    e1 += __shfl_xor(e1, 16); e1 += __shfl_xor(e1, 32);
    e2 += __shfl_xor(e2, 16); e2 += __shfl_xor(e2, 32);
    float mx = fmaxf(m_f[f], fmaxf(e1, e2));
    float w0 = exp2f(m_f[f] - mx);
    float w1 = exp2f(e1 - mx);
    float w2 = exp2f(e2 - mx);
    float inv = 1.0f / (l_p[f] * w0 + w1 + w2);
    float s0 = w0 * inv, s1 = w1 * inv, s2 = w2 * inv;
    // move per-row scalars (on lanes 0..15) to the O domain (row = lq*4+r)
    float a0[4], a1[4], a2[4];
#pragma unroll
    for (int r = 0; r < 4; r++) {
      a0[r] = __shfl(s0, lq * 4 + r);
      a1[r] = __shfl(s1, lq * 4 + r);
      a2[r] = __shfl(s2, lq * 4 + r);
    }
#pragma unroll
    for (int r = 0; r < 4; r++) {
      const int rowO = rb0 + f * 16 + lq * 4 + r;
      const float* v1p = v1base + (size_t)rowO * HD_;
      const float* vnp = vnbase + (size_t)rowO * 3072;
      unsigned short* aop = aobase + (size_t)rowO * (NH_ * HD_);
#pragma unroll
      for (int jd = 0; jd < 4; jd++) {
        int d = jd * 16 + la;
        float out = o[f][jd][r] * a0[r] + v1p[d] * a1[r] + vnp[d] * a2[r];
        aop[d] = f2bf(out);
      }
    }
  }
}

// ---------------------------------------------------------------------------
// Workspace layout (bytes; needs ws_size >= 178,257,920)
#define OFF_QKV   ((size_t)0)
#define OFF_XB    ((size_t)50331648)
#define OFF_WQKVT ((size_t)83886080)
#define OFF_WOT   ((size_t)109051904)
#define OFF_QB    ((size_t)117440512)
#define OFF_K0B   ((size_t)134217728)
#define OFF_V0T   ((size_t)150994944)
#define OFF_KNEW  ((size_t)167772160)
#define OFF_ML    ((size_t)176160768)

extern "C" void kernel_launch(void* const* d_in, const int* in_sizes, int n_in,
                              void* d_out, int out_size, void* d_ws, size_t ws_size,
                              hipStream_t stream) {
  const float* X = (const float*)d_in[0];
  const int* pos = (const int*)d_in[2];
  const float* prevk = (const float*)d_in[3];
  const float* prevv = (const float*)d_in[4];
  const float* Wq = (const float*)d_in[5];
  const float* Wk = (const float*)d_in[6];
  const float* Wv = (const float*)d_in[7];
  const float* Wo = (const float*)d_in[8];

  char* ws = (char*)d_ws;
  float* QKV = (float*)(ws + OFF_QKV);
  unsigned short* Xb = (unsigned short*)(ws + OFF_XB);
  unsigned short* WqkvT = (unsigned short*)(ws + OFF_WQKVT);
  unsigned short* attnout = (unsigned short*)(ws + OFF_WQKVT);
  unsigned short* WoT = (unsigned short*)(ws + OFF_WOT);
  unsigned short* q_b = (unsigned short*)(ws + OFF_QB);
  unsigned short* k0b = (unsigned short*)(ws + OFF_K0B);
  unsigned short* v0t = (unsigned short*)(ws + OFF_V0T);
  float* knew = (float*)(ws + OFF_KNEW);

  convert_bf16<<<16384, 256, 0, stream>>>(X, Xb, 4194304);
  transpose_f32_bf16_ld<<<dim3(32, 64), 256, 0, stream>>>(Wq, WqkvT, 4096, 2048, 4096);
  transpose_f32_bf16_ld<<<dim3(8, 64), 256, 0, stream>>>(Wk, WqkvT + (size_t)2048 * 4096, 4096, 512, 4096);
  transpose_f32_bf16_ld<<<dim3(8, 64), 256, 0, stream>>>(Wv, WqkvT + (size_t)2560 * 4096, 4096, 512, 4096);
  transpose_f32_bf16_ld<<<dim3(32, 32), 256, 0, stream>>>(Wo, WoT, 2048, 2048, 2048);
  convert_bf16<<<8192, 256, 0, stream>>>(prevk, k0b, 2097152);
  transpose_v0<<<dim3(32, 64), 256, 0, stream>>>(prevv, v0t);

  // QKV GEMM: M=4096, N=3072, K=4096; BM=128, BN=384 -> grid 32x8 = 256
  gemm128_bt<6><<<dim3(32, 8), 512, 0, stream>>>(Xb, WqkvT, QKV, 4096, 3072, 4096);

  rope_kernel<<<20480, 256, 0, stream>>>(QKV, pos, q_b, knew);

  // flash with fused diagonal-key epilogue -> writes attnout bf16 directly
  flash_kernel<<<1024, 256, 0, stream>>>(q_b, k0b, v0t, prevk, prevv, knew, QKV, attnout);

  // Wo GEMM: M=4096, N=2048, K=2048; BM=128, BN=256 -> grid 32x8 = 256
  gemm128_bt<4><<<dim3(32, 8), 512, 0, stream>>>(attnout, WoT, (float*)d_out, 4096, 2048, 2048);
}